// Round 3
// baseline (485.357 us; speedup 1.0000x reference)
//
#include <hip/hip_runtime.h>
#include <stdint.h>
#include <string.h>

#define N_USER 50000
#define N_ITEM 50000
#define N_EDGE 600000
#define D 128
#define NTOT 150000      // 3 * 50000 destination slots (uu | ub | iu)
#define ETOT 1800000
#define NB 147           // buckets = ceil(NTOT / SPAN)
#define BSH 10
#define SPAN 1024        // slots per bucket
#define CHUNK 4096       // edges per block in bucket kernels (16/thread)
#define CROWS 1600000    // u16 per feature chunk table (50000 rows * 32 elems)

typedef unsigned short u16;
typedef unsigned int   u32;
typedef __attribute__((ext_vector_type(8))) short short8;   // 8 bf16 (MFMA A/B frag)
typedef __attribute__((ext_vector_type(4))) float floatx4;  // MFMA C/D frag

static __device__ __forceinline__ u16 f2b(float f) {        // f32 -> bf16 RNE
  u32 x; memcpy(&x, &f, 4);
  u32 r = x + 0x7fffu + ((x >> 16) & 1u);
  return (u16)(r >> 16);
}
static __device__ __forceinline__ float blo2f(u32 v) {
  u32 x = v << 16; float f; memcpy(&f, &x, 4); return f;
}
static __device__ __forceinline__ float bhi2f(u32 v) {
  u32 x = v & 0xffff0000u; float f; memcpy(&f, &x, 4); return f;
}

// ---- front: [0,440) edge-bucket histogram | [440,443) weight transpose | rest:
//      f32->bf16 feature conversion into CHUNK-MAJOR tables (4 x 3.2MB per tensor,
//      each chunk table fits a 4MB per-XCD L2 for the gather phase) ----
__global__ void __launch_bounds__(256) k_front(
    const int* __restrict__ duu, const int* __restrict__ dub, const int* __restrict__ diu,
    int* __restrict__ bhist,
    const float* __restrict__ W0, const float* __restrict__ W1, const float* __restrict__ W2,
    u16* __restrict__ WT,
    const float* __restrict__ fu, const float* __restrict__ fi,
    u16* __restrict__ fbc_u, u16* __restrict__ fbc_i) {
  int bid = blockIdx.x;
  if (bid < 440) {                       // bucket histogram
    __shared__ int h[NB];
    for (int i = threadIdx.x; i < NB; i += 256) h[i] = 0;
    __syncthreads();
    int base = bid * CHUNK;
    for (int j = threadIdx.x; j < CHUNK; j += 256) {
      int e = base + j;
      if (e < ETOT) {
        int t = e / N_EDGE, i = e - t * N_EDGE;
        int d = (t == 0) ? duu[i] : ((t == 1) ? dub[i] : diu[i]);
        atomicAdd(&h[(t * N_USER + d) >> BSH], 1);
      }
    }
    __syncthreads();
    for (int i = threadIdx.x; i < NB; i += 256) if (h[i]) atomicAdd(&bhist[i], h[i]);
  } else if (bid < 443) {                // weight transpose + bf16
    int wsel = bid - 440;
    const float* W = (wsel == 0) ? W0 : ((wsel == 1) ? W1 : W2);
    u16* T = WT + wsel * D * D;
    for (int idx = threadIdx.x; idx < D * D; idx += 256) {
      int n = idx >> 7, k = idx & 127;
      T[idx] = f2b(W[k * D + n]);
    }
  } else {                               // feature conversion, chunk-major
    int g = bid - 443;
    const float* src = fu; u16* dst = fbc_u;
    if (g >= 6250) { g -= 6250; src = fi; dst = fbc_i; }
    int gid = g * 256 + threadIdx.x;     // float4 group: elems [4j,4j+4) of row `node`
    float4 v = ((const float4*)src)[gid];
    int node = gid >> 5, j = gid & 31;
    int c = j >> 3;                      // chunk = 32 elems = 8 float4 groups
    union { u16 u[4]; uint2 d; } pk;
    pk.u[0] = f2b(v.x); pk.u[1] = f2b(v.y); pk.u[2] = f2b(v.z); pk.u[3] = f2b(v.w);
    ((uint2*)dst)[c * 400000 + node * 8 + (j & 7)] = pk.d;
  }
}

// ---- place edges into bucket-grouped ebuf; each block re-derives the bucket scan
//      locally from bhist (replaces the k_bscan launch); block 0 publishes boff ----
__global__ void __launch_bounds__(256) k_bplace(
    const int* __restrict__ suu, const int* __restrict__ duu,
    const int* __restrict__ sub, const int* __restrict__ dub,
    const int* __restrict__ siu, const int* __restrict__ diu,
    const int* __restrict__ bhist, int* __restrict__ cursor,
    int* __restrict__ boff, u32* __restrict__ ebuf) {
  __shared__ int h[NB];
  __shared__ int sboff[NB];
  __shared__ int buf[256];
  int t = threadIdx.x;
  int v = (t < NB) ? bhist[t] : 0;
  buf[t] = v; __syncthreads();
  for (int s = 1; s < 256; s <<= 1) {
    int y = (t >= s) ? buf[t - s] : 0;
    __syncthreads(); buf[t] += y; __syncthreads();
  }
  if (t < NB) sboff[t] = (t == 0) ? 0 : buf[t - 1];
  if (blockIdx.x == 0 && t <= NB) boff[t] = (t == 0) ? 0 : buf[t - 1];
  for (int i = t; i < NB; i += 256) h[i] = 0;
  __syncthreads();
  int base = blockIdx.x * CHUNK;
  u32 pay[16], br[16];
#pragma unroll
  for (int k = 0; k < 16; ++k) {
    int e = base + k * 256 + t;
    br[k] = 0xFFFFFFFFu;
    if (e < ETOT) {
      int ty = e / N_EDGE, i = e - ty * N_EDGE;
      int d, s;
      if (ty == 0)      { d = duu[i]; s = suu[i]; }
      else if (ty == 1) { d = dub[i]; s = sub[i]; }
      else              { d = diu[i]; s = siu[i]; }
      int slot = ty * N_USER + d;
      int bu = slot >> BSH;
      int rank = atomicAdd(&h[bu], 1);
      pay[k] = (u32)s | ((u32)(slot & (SPAN - 1)) << 16);
      br[k]  = (u32)bu | ((u32)rank << 8);       // bu<=146 fits 8 bits; rank<4096
    }
  }
  __syncthreads();
  for (int i = t; i < NB; i += 256)
    h[i] = sboff[i] + atomicAdd(&cursor[i], h[i]);    // block base within bucket region
  __syncthreads();
#pragma unroll
  for (int k = 0; k < 16; ++k) {
    if (br[k] != 0xFFFFFFFFu) {
      int bu = br[k] & 0xFF, rank = (int)(br[k] >> 8);
      ebuf[h[bu] + rank] = pay[k];
    }
  }
}

// ---- per-bucket CSR finalize: off[] (coalesced) + ssrc[] (L2-local scatter) ----
__global__ void __launch_bounds__(256) k_csr(const int* __restrict__ boff, const u32* __restrict__ ebuf,
                                             int* __restrict__ off, u16* __restrict__ ssrc) {
  __shared__ int sc[SPAN];
  __shared__ int so[SPAN];
  __shared__ int part[256];
  int b = blockIdx.x;
  int ebase = boff[b], ecnt = boff[b + 1] - ebase;
  int sbase = b << BSH;
  int nslots = (NTOT - sbase < SPAN) ? (NTOT - sbase) : SPAN;
  for (int i = threadIdx.x; i < SPAN; i += 256) sc[i] = 0;
  __syncthreads();
  for (int j = threadIdx.x; j < ecnt; j += 256)
    atomicAdd(&sc[ebuf[ebase + j] >> 16], 1);
  __syncthreads();
  int t = threadIdx.x;
  int s0 = sc[4*t], s1 = sc[4*t+1], s2 = sc[4*t+2], s3 = sc[4*t+3];
  int tsum = s0 + s1 + s2 + s3;
  part[t] = tsum; __syncthreads();
  for (int s = 1; s < 256; s <<= 1) {
    int y = (t >= s) ? part[t - s] : 0;
    __syncthreads(); part[t] += y; __syncthreads();
  }
  int pbase = part[t] - tsum;
  so[4*t]   = pbase;
  so[4*t+1] = pbase + s0;
  so[4*t+2] = pbase + s0 + s1;
  so[4*t+3] = pbase + s0 + s1 + s2;
  __syncthreads();
  for (int i = threadIdx.x; i < nslots; i += 256)
    off[sbase + i] = ebase + so[i];
  if (b == 0 && threadIdx.x == 0) off[NTOT] = ETOT;
  for (int i = threadIdx.x; i < SPAN; i += 256) sc[i] = so[i];   // cursors
  __syncthreads();
  for (int j = threadIdx.x; j < ecnt; j += 256) {
    u32 p = ebuf[ebase + j];
    int pos = atomicAdd(&sc[p >> 16], 1);
    ssrc[ebase + pos] = (u16)(p & 0xFFFFu);
  }
}

// ---- chunk-phased gather-mean: grid = 4 chunks x (25000 user-table + 12500 item-table)
//      blocks. Active gather footprint per phase = one 3.2MB chunk table -> per-XCD L2.
//      Wave = 4 edges x 16 feature-lanes; shfl_xor(16,32) reduce; means -> d_out bf16. ----
__global__ void __launch_bounds__(256) k_mean(const u16* __restrict__ fbc_u, const u16* __restrict__ fbc_i,
                                              const int* __restrict__ off, const u16* __restrict__ ssrc,
                                              u16* __restrict__ ob) {
  int c = blockIdx.x / 37500;        // chunk phase 0..3
  int b = blockIdx.x % 37500;
  int w = threadIdx.x >> 6;          // wave -> one slot
  int lane = threadIdx.x & 63;
  int g = lane >> 4, f = lane & 15;  // edge-group, feature-lane (u32 = 2 bf16)
  int slot, t;
  const u16* fbc;
  if (b < 25000) { slot = b * 4 + w; t = slot / N_USER; fbc = fbc_u + (size_t)c * CROWS; }
  else           { slot = 100000 + (b - 25000) * 4 + w; t = 2; fbc = fbc_i + (size_t)c * CROWS; }
  int d = slot - t * N_USER;
  int s = off[slot], e = off[slot + 1];
  float a0 = 0.f, a1 = 0.f;
  for (int i = s + g; i < e; i += 4) {
    int sr = ssrc[i];
    u32 v = ((const u32*)(fbc + (size_t)sr * 32))[f];
    a0 += blo2f(v); a1 += bhi2f(v);
  }
  a0 += __shfl_xor(a0, 16); a0 += __shfl_xor(a0, 32);
  a1 += __shfl_xor(a1, 16); a1 += __shfl_xor(a1, 32);
  if (g == 0) {
    int n = e - s;
    float inv = (n > 0) ? 1.0f / (float)n : 0.f;
    u32 pk = (u32)f2b(a0 * inv) | ((u32)f2b(a1 * inv) << 16);
    u32* mrow;
    if (t == 0)      mrow = (u32*)(ob + (size_t)d * 256);              // mean_uu: row 1st half
    else if (t == 2) mrow = (u32*)(ob + (size_t)d * 256 + 128);        // mean_iu: row 2nd half
    else             mrow = (u32*)(ob + 12800000 + (size_t)d * 256);   // mean_ub: item row
    mrow[c * 16 + f] = pk;
  }
}

// ---- final GEMM, single launch, in-place on d_out: each block reads the bf16 means
//      stored in its own output rows, then overwrites those rows with f32 results ----
__global__ void __launch_bounds__(256) k_out(float* out, const u16* __restrict__ WT,
                                             const float* __restrict__ buu, const float* __restrict__ bub,
                                             const float* __restrict__ biu, const int* __restrict__ off) {
  int users = (blockIdx.y == 0);
  int tid = threadIdx.x;
  int w = tid >> 6, lane = tid & 63, quad = lane >> 4, l16 = lane & 15;
  int row_base = blockIdx.x * 64;
  int r0 = row_base + w * 16 + l16;
  int rA = r0 < N_USER ? r0 : N_USER - 1;
  const u16* ob = (const u16*)out;

  // calibration MFMA: recover (row,col) mapping of C/D fragment registers
  short8 apb, bpb;
#pragma unroll
  for (int j = 0; j < 8; j++) {
    int k = quad * 8 + j;
    apb[j] = (short)((k == l16) ? 0x3F80 : 0);
    bpb[j] = (short)((k < 16) ? f2b((float)(k * 16 + l16)) : 0);
  }
  floatx4 pz = (floatx4){0.f, 0.f, 0.f, 0.f};
  floatx4 pr = __builtin_amdgcn_mfma_f32_16x16x32_bf16(apb, bpb, pz, 0, 0, 0);
  int rowm[4], colm[4];
#pragma unroll
  for (int i = 0; i < 4; i++) { int v = (int)pr[i]; rowm[i] = v >> 4; colm[i] = v & 15; }

  floatx4 acc[8];
#pragma unroll
  for (int i = 0; i < 8; i++) acc[i] = (floatx4){0.f, 0.f, 0.f, 0.f};

  {
    const u16* A0 = users ? (ob + (size_t)rA * 256)
                          : (ob + 12800000 + (size_t)rA * 256);
    const u16* W0 = users ? WT : (WT + D * D);
    const short8* aptr = (const short8*)(A0 + quad * 8);
#pragma unroll
    for (int kk = 0; kk < 4; ++kk) {
      short8 af = aptr[kk * 4];
      const short8* bptr = (const short8*)(W0 + l16 * D + kk * 32 + quad * 8);
#pragma unroll
      for (int nt = 0; nt < 8; ++nt)
        acc[nt] = __builtin_amdgcn_mfma_f32_16x16x32_bf16(af, bptr[nt * 256], acc[nt], 0, 0, 0);
    }
  }
  if (users) {
    const short8* aptr = (const short8*)(ob + (size_t)rA * 256 + 128 + quad * 8);
    const u16* W2 = WT + 2 * D * D;
#pragma unroll
    for (int kk = 0; kk < 4; ++kk) {
      short8 af = aptr[kk * 4];
      const short8* bptr = (const short8*)(W2 + l16 * D + kk * 32 + quad * 8);
#pragma unroll
      for (int nt = 0; nt < 8; ++nt)
        acc[nt] = __builtin_amdgcn_mfma_f32_16x16x32_bf16(af, bptr[nt * 256], acc[nt], 0, 0, 0);
    }
  }

  __shared__ float lds[64 * 132];
#pragma unroll
  for (int nt = 0; nt < 8; ++nt)
#pragma unroll
    for (int r = 0; r < 4; ++r)
      lds[(w * 16 + rowm[r]) * 132 + nt * 16 + colm[r]] = acc[nt][r];
  __syncthreads();

#pragma unroll
  for (int i = 0; i < 4; i++) {
    int linear = tid + i * 256;
    int row = linear >> 4;
    int cg  = (linear & 15) * 8;
    int grow = row_base + row;
    if (grow < N_USER) {
      float res[8];
      if (users) {
        int n0 = off[grow + 1] - off[grow];
        int n2 = off[2 * N_USER + grow + 1] - off[2 * N_USER + grow];
#pragma unroll
        for (int j = 0; j < 8; j++) {
          float b = (n0 > 0 ? buu[cg + j] : 0.f) + (n2 > 0 ? biu[cg + j] : 0.f);
          res[j] = lds[row * 132 + cg + j] + b;
        }
        float4* dst = (float4*)(out + (size_t)grow * D + cg);
        dst[0] = make_float4(res[0], res[1], res[2], res[3]);
        dst[1] = make_float4(res[4], res[5], res[6], res[7]);
      } else {
        int n1 = off[N_USER + grow + 1] - off[N_USER + grow];
#pragma unroll
        for (int j = 0; j < 8; j++) {
          float b = (n1 > 0 ? bub[cg + j] : 0.f);
          res[j] = lds[row * 132 + cg + j] + b;
        }
        float4* dst = (float4*)(out + (size_t)(N_USER + grow) * D + cg);
        dst[0] = make_float4(res[0], res[1], res[2], res[3]);
        dst[1] = make_float4(res[4], res[5], res[6], res[7]);
      }
    }
  }
}

extern "C" void kernel_launch(void* const* d_in, const int* in_sizes, int n_in,
                              void* d_out, int out_size, void* d_ws, size_t ws_size,
                              hipStream_t stream) {
  const float* fu  = (const float*)d_in[0];
  const float* fi  = (const float*)d_in[1];
  const float* Wuu = (const float*)d_in[2];
  const float* buu = (const float*)d_in[3];
  const float* Wub = (const float*)d_in[4];
  const float* bub = (const float*)d_in[5];
  const float* Wiu = (const float*)d_in[6];
  const float* biu = (const float*)d_in[7];
  const int* suu = (const int*)d_in[8];
  const int* duu = (const int*)d_in[9];
  const int* sub = (const int*)d_in[10];
  const int* dub = (const int*)d_in[11];
  const int* siu = (const int*)d_in[12];
  const int* diu = (const int*)d_in[13];
  float* out = (float*)d_out;   // f32: [out_user 50000x128 | out_item 50000x128]
  u16* ob = (u16*)d_out;
  // d_out scratch (race-free): k_mean writes bf16 means INTO the output rows
  //   user row r: [0,256B)=mean_uu, [256B,512B)=mean_iu ; item row r: [0,256B)=mean_ub
  // k_out reads only its own rows' means, then overwrites those rows (read-before-write
  // within each block; rows disjoint across blocks; clamp row 49999 is self-owned).

  // workspace layout (37.1 MB) -- UNIT-CHECKED in INTs this time:
  //   WT needs 49,152 u16 = 24,576 ints -> fbc_u starts at 2,850,592 + 24,576 = 2,875,168
  //   fbc_u = 6,400,000 u16 = 3,200,000 ints -> fbc_i at 6,075,168; ends 9,275,168 ints = 37.1 MB
  int* wsi    = (int*)d_ws;
  int* off    = wsi;                        // [150001] -> pad to 150016
  int* bhist  = wsi + 150016;               // [147]
  int* cursor = wsi + 150208;               // [147]
  int* boff   = wsi + 150400;               // [148]
  u32* ebuf   = (u32*)(wsi + 150592);       // [1800000] (7.2 MB)
  u16* ssrc   = (u16*)(wsi + 1950592);      // [1800000] u16 (3.6 MB)
  u16* WT     = (u16*)(wsi + 2850592);      // 3*128*128 bf16 (96 KB = 24,576 ints)
  u16* fbc_u  = (u16*)(wsi + 2875168);      // 4 chunk tables x 3.2MB (12.8 MB)
  u16* fbc_i  = (u16*)(wsi + 6075168);      // 4 chunk tables x 3.2MB (12.8 MB)

  hipMemsetAsync(bhist, 0, 384 * sizeof(int), stream);   // bhist + cursor
  k_front<<<443 + 12500, 256, 0, stream>>>(duu, dub, diu, bhist, Wuu, Wub, Wiu, WT,
                                           fu, fi, fbc_u, fbc_i);
  k_bplace<<<440, 256, 0, stream>>>(suu, duu, sub, dub, siu, diu, bhist, cursor, boff, ebuf);
  k_csr<<<NB, 256, 0, stream>>>(boff, ebuf, off, ssrc);
  k_mean<<<150000, 256, 0, stream>>>(fbc_u, fbc_i, off, ssrc, ob);
  k_out<<<dim3(782, 2), 256, 0, stream>>>(out, WT, buu, bub, biu, off);
}

// Round 5
// 330.356 us; speedup vs baseline: 1.4692x; 1.4692x over previous
//
#include <hip/hip_runtime.h>
#include <stdint.h>
#include <string.h>

#define N_USER 50000
#define N_ITEM 50000
#define N_EDGE 600000
#define D 128
#define NTOT 150000      // 3 * 50000 destination slots (uu | ub | iu)
#define ETOT 1800000
#define NB 147           // buckets = ceil(NTOT / SPAN)
#define BSH 10
#define SPAN 1024        // slots per bucket
#define CHUNK 4096       // edges per block in bucket kernels (16/thread)

typedef unsigned short u16;
typedef unsigned int   u32;
typedef __attribute__((ext_vector_type(8))) short short8;   // 8 bf16 (MFMA A/B frag)
typedef __attribute__((ext_vector_type(4))) float floatx4;  // MFMA C/D frag

static __device__ __forceinline__ u16 f2b(float f) {        // f32 -> bf16 RNE
  u32 x; memcpy(&x, &f, 4);
  u32 r = x + 0x7fffu + ((x >> 16) & 1u);
  return (u16)(r >> 16);
}
static __device__ __forceinline__ float blo2f(u32 v) {
  u32 x = v << 16; float f; memcpy(&f, &x, 4); return f;
}
static __device__ __forceinline__ float bhi2f(u32 v) {
  u32 x = v & 0xffff0000u; float f; memcpy(&f, &x, 4); return f;
}

// ---- front: [0,440) edge-bucket histogram | [440,443) weight transpose | rest:
//      f32->bf16 feature conversion into ROW-MAJOR bf16 tables (chunking refuted r3) ----
__global__ void __launch_bounds__(256) k_front(
    const int* __restrict__ duu, const int* __restrict__ dub, const int* __restrict__ diu,
    int* __restrict__ bhist,
    const float* __restrict__ W0, const float* __restrict__ W1, const float* __restrict__ W2,
    u16* __restrict__ WT,
    const float* __restrict__ fu, const float* __restrict__ fi,
    u16* __restrict__ fb_u, u16* __restrict__ fb_i) {
  int bid = blockIdx.x;
  if (bid < 440) {                       // bucket histogram
    __shared__ int h[NB];
    for (int i = threadIdx.x; i < NB; i += 256) h[i] = 0;
    __syncthreads();
    int base = bid * CHUNK;
    for (int j = threadIdx.x; j < CHUNK; j += 256) {
      int e = base + j;
      if (e < ETOT) {
        int t = e / N_EDGE, i = e - t * N_EDGE;
        int d = (t == 0) ? duu[i] : ((t == 1) ? dub[i] : diu[i]);
        atomicAdd(&h[(t * N_USER + d) >> BSH], 1);
      }
    }
    __syncthreads();
    for (int i = threadIdx.x; i < NB; i += 256) if (h[i]) atomicAdd(&bhist[i], h[i]);
  } else if (bid < 443) {                // weight transpose + bf16
    int wsel = bid - 440;
    const float* W = (wsel == 0) ? W0 : ((wsel == 1) ? W1 : W2);
    u16* T = WT + wsel * D * D;
    for (int idx = threadIdx.x; idx < D * D; idx += 256) {
      int n = idx >> 7, k = idx & 127;
      T[idx] = f2b(W[k * D + n]);
    }
  } else {                               // feature conversion, row-major
    int g = bid - 443;
    const float* src = fu; u16* dst = fb_u;
    if (g >= 6250) { g -= 6250; src = fi; dst = fb_i; }
    int gid = g * 256 + threadIdx.x;     // float4 groups: 1.6M per tensor
    float4 v = ((const float4*)src)[gid];
    union { u16 u[4]; uint2 d; } pk;
    pk.u[0] = f2b(v.x); pk.u[1] = f2b(v.y); pk.u[2] = f2b(v.z); pk.u[3] = f2b(v.w);
    ((uint2*)dst)[gid] = pk.d;
  }
}

// ---- place edges into bucket-grouped ebuf; each block re-derives the bucket scan
//      locally from bhist (replaces the k_bscan launch); block 0 publishes boff ----
__global__ void __launch_bounds__(256) k_bplace(
    const int* __restrict__ suu, const int* __restrict__ duu,
    const int* __restrict__ sub, const int* __restrict__ dub,
    const int* __restrict__ siu, const int* __restrict__ diu,
    const int* __restrict__ bhist, int* __restrict__ cursor,
    int* __restrict__ boff, u32* __restrict__ ebuf) {
  __shared__ int h[NB];
  __shared__ int sboff[NB];
  __shared__ int buf[256];
  int t = threadIdx.x;
  int v = (t < NB) ? bhist[t] : 0;
  buf[t] = v; __syncthreads();
  for (int s = 1; s < 256; s <<= 1) {
    int y = (t >= s) ? buf[t - s] : 0;
    __syncthreads(); buf[t] += y; __syncthreads();
  }
  if (t < NB) sboff[t] = (t == 0) ? 0 : buf[t - 1];
  if (blockIdx.x == 0 && t <= NB) boff[t] = (t == 0) ? 0 : buf[t - 1];
  for (int i = t; i < NB; i += 256) h[i] = 0;
  __syncthreads();
  int base = blockIdx.x * CHUNK;
  u32 pay[16], br[16];
#pragma unroll
  for (int k = 0; k < 16; ++k) {
    int e = base + k * 256 + t;
    br[k] = 0xFFFFFFFFu;
    if (e < ETOT) {
      int ty = e / N_EDGE, i = e - ty * N_EDGE;
      int d, s;
      if (ty == 0)      { d = duu[i]; s = suu[i]; }
      else if (ty == 1) { d = dub[i]; s = sub[i]; }
      else              { d = diu[i]; s = siu[i]; }
      int slot = ty * N_USER + d;
      int bu = slot >> BSH;
      int rank = atomicAdd(&h[bu], 1);
      pay[k] = (u32)s | ((u32)(slot & (SPAN - 1)) << 16);
      br[k]  = (u32)bu | ((u32)rank << 8);       // bu<=146 fits 8 bits; rank<4096
    }
  }
  __syncthreads();
  for (int i = t; i < NB; i += 256)
    h[i] = sboff[i] + atomicAdd(&cursor[i], h[i]);    // block base within bucket region
  __syncthreads();
#pragma unroll
  for (int k = 0; k < 16; ++k) {
    if (br[k] != 0xFFFFFFFFu) {
      int bu = br[k] & 0xFF, rank = (int)(br[k] >> 8);
      ebuf[h[bu] + rank] = pay[k];
    }
  }
}

// ---- per-bucket CSR finalize: off[] (coalesced) + ssrc[] (L2-local scatter) ----
__global__ void __launch_bounds__(256) k_csr(const int* __restrict__ boff, const u32* __restrict__ ebuf,
                                             int* __restrict__ off, u16* __restrict__ ssrc) {
  __shared__ int sc[SPAN];
  __shared__ int so[SPAN];
  __shared__ int part[256];
  int b = blockIdx.x;
  int ebase = boff[b], ecnt = boff[b + 1] - ebase;
  int sbase = b << BSH;
  int nslots = (NTOT - sbase < SPAN) ? (NTOT - sbase) : SPAN;
  for (int i = threadIdx.x; i < SPAN; i += 256) sc[i] = 0;
  __syncthreads();
  for (int j = threadIdx.x; j < ecnt; j += 256)
    atomicAdd(&sc[ebuf[ebase + j] >> 16], 1);
  __syncthreads();
  int t = threadIdx.x;
  int s0 = sc[4*t], s1 = sc[4*t+1], s2 = sc[4*t+2], s3 = sc[4*t+3];
  int tsum = s0 + s1 + s2 + s3;
  part[t] = tsum; __syncthreads();
  for (int s = 1; s < 256; s <<= 1) {
    int y = (t >= s) ? part[t - s] : 0;
    __syncthreads(); part[t] += y; __syncthreads();
  }
  int pbase = part[t] - tsum;
  so[4*t]   = pbase;
  so[4*t+1] = pbase + s0;
  so[4*t+2] = pbase + s0 + s1;
  so[4*t+3] = pbase + s0 + s1 + s2;
  __syncthreads();
  for (int i = threadIdx.x; i < nslots; i += 256)
    off[sbase + i] = ebase + so[i];
  if (b == 0 && threadIdx.x == 0) off[NTOT] = ETOT;
  for (int i = threadIdx.x; i < SPAN; i += 256) sc[i] = so[i];   // cursors
  __syncthreads();
  for (int j = threadIdx.x; j < ecnt; j += 256) {
    u32 p = ebuf[ebase + j];
    int pos = atomicAdd(&sc[p >> 16], 1);
    ssrc[ebase + pos] = (u16)(p & 0xFFFFu);
  }
}

// ---- gather-mean: HALF-wave (32 lanes) per slot, uint2 (8B) per lane per row,
//      4-edge unrolled for ILP. 2 slots/wave, 8 slots/block. Means -> d_out bf16. ----
__global__ void __launch_bounds__(256) k_mean(const u16* __restrict__ fb_u, const u16* __restrict__ fb_i,
                                              const int* __restrict__ off, const u16* __restrict__ ssrc,
                                              u16* __restrict__ ob) {
  int slot = blockIdx.x * 8 + (threadIdx.x >> 5);
  int lane = threadIdx.x & 31;
  if (slot >= NTOT) return;
  int t = slot / N_USER;
  int d = slot - t * N_USER;
  const u16* fb = (t == 2) ? fb_i : fb_u;
  int s = off[slot], e = off[slot + 1];
  float a0 = 0.f, a1 = 0.f, a2 = 0.f, a3 = 0.f;
  int i = s;
  for (; i + 4 <= e; i += 4) {
    int s0 = ssrc[i], s1 = ssrc[i + 1], s2 = ssrc[i + 2], s3 = ssrc[i + 3];
    uint2 v0 = ((const uint2*)(fb + (size_t)s0 * D))[lane];
    uint2 v1 = ((const uint2*)(fb + (size_t)s1 * D))[lane];
    uint2 v2 = ((const uint2*)(fb + (size_t)s2 * D))[lane];
    uint2 v3 = ((const uint2*)(fb + (size_t)s3 * D))[lane];
    a0 += blo2f(v0.x) + blo2f(v1.x) + blo2f(v2.x) + blo2f(v3.x);
    a1 += bhi2f(v0.x) + bhi2f(v1.x) + bhi2f(v2.x) + bhi2f(v3.x);
    a2 += blo2f(v0.y) + blo2f(v1.y) + blo2f(v2.y) + blo2f(v3.y);
    a3 += bhi2f(v0.y) + bhi2f(v1.y) + bhi2f(v2.y) + bhi2f(v3.y);
  }
  for (; i < e; ++i) {
    uint2 v = ((const uint2*)(fb + (size_t)ssrc[i] * D))[lane];
    a0 += blo2f(v.x); a1 += bhi2f(v.x);
    a2 += blo2f(v.y); a3 += bhi2f(v.y);
  }
  int n = e - s;
  float inv = (n > 0) ? 1.0f / (float)n : 0.f;
  u32 p0 = (u32)f2b(a0 * inv) | ((u32)f2b(a1 * inv) << 16);
  u32 p1 = (u32)f2b(a2 * inv) | ((u32)f2b(a3 * inv) << 16);
  u32* mrow;
  if (t == 0)      mrow = (u32*)(ob + (size_t)d * 256);              // mean_uu: row 1st half
  else if (t == 2) mrow = (u32*)(ob + (size_t)d * 256 + 128);        // mean_iu: row 2nd half
  else             mrow = (u32*)(ob + 12800000 + (size_t)d * 256);   // mean_ub: item row
  ((uint2*)mrow)[lane] = make_uint2(p0, p1);
}

// ---- final GEMM, single launch, in-place on d_out: each block reads the bf16 means
//      stored in its own output rows, then overwrites those rows with f32 results ----
__global__ void __launch_bounds__(256) k_out(float* out, const u16* __restrict__ WT,
                                             const float* __restrict__ buu, const float* __restrict__ bub,
                                             const float* __restrict__ biu, const int* __restrict__ off) {
  int users = (blockIdx.y == 0);
  int tid = threadIdx.x;
  int w = tid >> 6, lane = tid & 63, quad = lane >> 4, l16 = lane & 15;
  int row_base = blockIdx.x * 64;
  int r0 = row_base + w * 16 + l16;
  int rA = r0 < N_USER ? r0 : N_USER - 1;
  const u16* ob = (const u16*)out;

  // calibration MFMA: recover (row,col) mapping of C/D fragment registers
  short8 apb, bpb;
#pragma unroll
  for (int j = 0; j < 8; j++) {
    int k = quad * 8 + j;
    apb[j] = (short)((k == l16) ? 0x3F80 : 0);
    bpb[j] = (short)((k < 16) ? f2b((float)(k * 16 + l16)) : 0);
  }
  floatx4 pz = (floatx4){0.f, 0.f, 0.f, 0.f};
  floatx4 pr = __builtin_amdgcn_mfma_f32_16x16x32_bf16(apb, bpb, pz, 0, 0, 0);
  int rowm[4], colm[4];
#pragma unroll
  for (int i = 0; i < 4; i++) { int v = (int)pr[i]; rowm[i] = v >> 4; colm[i] = v & 15; }

  floatx4 acc[8];
#pragma unroll
  for (int i = 0; i < 8; i++) acc[i] = (floatx4){0.f, 0.f, 0.f, 0.f};

  {
    const u16* A0 = users ? (ob + (size_t)rA * 256)
                          : (ob + 12800000 + (size_t)rA * 256);
    const u16* W0 = users ? WT : (WT + D * D);
    const short8* aptr = (const short8*)(A0 + quad * 8);
#pragma unroll
    for (int kk = 0; kk < 4; ++kk) {
      short8 af = aptr[kk * 4];
      const short8* bptr = (const short8*)(W0 + l16 * D + kk * 32 + quad * 8);
#pragma unroll
      for (int nt = 0; nt < 8; ++nt)
        acc[nt] = __builtin_amdgcn_mfma_f32_16x16x32_bf16(af, bptr[nt * 256], acc[nt], 0, 0, 0);
    }
  }
  if (users) {
    const short8* aptr = (const short8*)(ob + (size_t)rA * 256 + 128 + quad * 8);
    const u16* W2 = WT + 2 * D * D;
#pragma unroll
    for (int kk = 0; kk < 4; ++kk) {
      short8 af = aptr[kk * 4];
      const short8* bptr = (const short8*)(W2 + l16 * D + kk * 32 + quad * 8);
#pragma unroll
      for (int nt = 0; nt < 8; ++nt)
        acc[nt] = __builtin_amdgcn_mfma_f32_16x16x32_bf16(af, bptr[nt * 256], acc[nt], 0, 0, 0);
    }
  }

  __shared__ float lds[64 * 132];
#pragma unroll
  for (int nt = 0; nt < 8; ++nt)
#pragma unroll
    for (int r = 0; r < 4; ++r)
      lds[(w * 16 + rowm[r]) * 132 + nt * 16 + colm[r]] = acc[nt][r];
  __syncthreads();

#pragma unroll
  for (int i = 0; i < 4; i++) {
    int linear = tid + i * 256;
    int row = linear >> 4;
    int cg  = (linear & 15) * 8;
    int grow = row_base + row;
    if (grow < N_USER) {
      float res[8];
      if (users) {
        int n0 = off[grow + 1] - off[grow];
        int n2 = off[2 * N_USER + grow + 1] - off[2 * N_USER + grow];
#pragma unroll
        for (int j = 0; j < 8; j++) {
          float b = (n0 > 0 ? buu[cg + j] : 0.f) + (n2 > 0 ? biu[cg + j] : 0.f);
          res[j] = lds[row * 132 + cg + j] + b;
        }
        float4* dst = (float4*)(out + (size_t)grow * D + cg);
        dst[0] = make_float4(res[0], res[1], res[2], res[3]);
        dst[1] = make_float4(res[4], res[5], res[6], res[7]);
      } else {
        int n1 = off[N_USER + grow + 1] - off[N_USER + grow];
#pragma unroll
        for (int j = 0; j < 8; j++) {
          float b = (n1 > 0 ? bub[cg + j] : 0.f);
          res[j] = lds[row * 132 + cg + j] + b;
        }
        float4* dst = (float4*)(out + (size_t)(N_USER + grow) * D + cg);
        dst[0] = make_float4(res[0], res[1], res[2], res[3]);
        dst[1] = make_float4(res[4], res[5], res[6], res[7]);
      }
    }
  }
}

extern "C" void kernel_launch(void* const* d_in, const int* in_sizes, int n_in,
                              void* d_out, int out_size, void* d_ws, size_t ws_size,
                              hipStream_t stream) {
  const float* fu  = (const float*)d_in[0];
  const float* fi  = (const float*)d_in[1];
  const float* Wuu = (const float*)d_in[2];
  const float* buu = (const float*)d_in[3];
  const float* Wub = (const float*)d_in[4];
  const float* bub = (const float*)d_in[5];
  const float* Wiu = (const float*)d_in[6];
  const float* biu = (const float*)d_in[7];
  const int* suu = (const int*)d_in[8];
  const int* duu = (const int*)d_in[9];
  const int* sub = (const int*)d_in[10];
  const int* dub = (const int*)d_in[11];
  const int* siu = (const int*)d_in[12];
  const int* diu = (const int*)d_in[13];
  float* out = (float*)d_out;   // f32: [out_user 50000x128 | out_item 50000x128]
  u16* ob = (u16*)d_out;
  // d_out scratch (race-free): k_mean writes bf16 means INTO the output rows
  //   user row r: [0,256B)=mean_uu, [256B,512B)=mean_iu ; item row r: [0,256B)=mean_ub
  // k_out reads only its own rows' means, then overwrites those rows (read-before-write
  // within each block; rows disjoint across blocks; clamp row 49999 is self-owned).

  // workspace layout (37.1 MB), offsets in INTs (verified r3):
  //   WT = 49,152 u16 = 24,576 ints; fb_u = 6,400,000 u16 = 3,200,000 ints
  int* wsi    = (int*)d_ws;
  int* off    = wsi;                        // [150001] -> pad to 150016
  int* bhist  = wsi + 150016;               // [147]
  int* cursor = wsi + 150208;               // [147]
  int* boff   = wsi + 150400;               // [148]
  u32* ebuf   = (u32*)(wsi + 150592);       // [1800000] (7.2 MB)
  u16* ssrc   = (u16*)(wsi + 1950592);      // [1800000] u16 (3.6 MB)
  u16* WT     = (u16*)(wsi + 2850592);      // 3*128*128 bf16 (96 KB = 24,576 ints)
  u16* fb_u   = (u16*)(wsi + 2875168);      // 50000x128 bf16 row-major (12.8 MB)
  u16* fb_i   = (u16*)(wsi + 6075168);      // 50000x128 bf16 row-major (12.8 MB)

  hipMemsetAsync(bhist, 0, 384 * sizeof(int), stream);   // bhist + cursor
  k_front<<<443 + 12500, 256, 0, stream>>>(duu, dub, diu, bhist, Wuu, Wub, Wiu, WT,
                                           fu, fi, fb_u, fb_i);
  k_bplace<<<440, 256, 0, stream>>>(suu, duu, sub, dub, siu, diu, bhist, cursor, boff, ebuf);
  k_csr<<<NB, 256, 0, stream>>>(boff, ebuf, off, ssrc);
  k_mean<<<18750, 256, 0, stream>>>(fb_u, fb_i, off, ssrc, ob);
  k_out<<<dim3(782, 2), 256, 0, stream>>>(out, WT, buu, bub, biu, off);
}

// Round 6
// 312.964 us; speedup vs baseline: 1.5508x; 1.0556x over previous
//
#include <hip/hip_runtime.h>
#include <stdint.h>
#include <string.h>

#define N_USER 50000
#define N_ITEM 50000
#define N_EDGE 600000
#define D 128
#define NTOT 150000      // 3 * 50000 destination slots (uu | ub | iu)
#define ETOT 1800000
#define NB 147           // buckets = ceil(NTOT / SPAN)
#define BSH 10
#define SPAN 1024        // slots per bucket
#define CHUNK 4096       // edges per block in bucket kernels (16/thread)

typedef unsigned short u16;
typedef unsigned int   u32;
typedef __attribute__((ext_vector_type(8))) short short8;   // 8 bf16 (MFMA A/B frag)
typedef __attribute__((ext_vector_type(4))) float floatx4;  // MFMA C/D frag

static __device__ __forceinline__ u16 f2b(float f) {        // f32 -> bf16 RNE
  u32 x; memcpy(&x, &f, 4);
  u32 r = x + 0x7fffu + ((x >> 16) & 1u);
  return (u16)(r >> 16);
}
static __device__ __forceinline__ float blo2f(u32 v) {
  u32 x = v << 16; float f; memcpy(&f, &x, 4); return f;
}
static __device__ __forceinline__ float bhi2f(u32 v) {
  u32 x = v & 0xffff0000u; float f; memcpy(&f, &x, 4); return f;
}

// ---- front: [0,440) edge-bucket histogram | [440,443) weight transpose (stacked) |
//      rest: f32->bf16 feature conversion into ROW-MAJOR bf16 tables ----
// WTu = [W_uu ; W_iu]^T as [n=128][k=256] (user GEMM is K=256 over [mean_uu|mean_iu]).
// WTi = W_ub^T as [n=128][k=128], at WT + 32768 u16.
__global__ void __launch_bounds__(256) k_front(
    const int* __restrict__ duu, const int* __restrict__ dub, const int* __restrict__ diu,
    int* __restrict__ bhist,
    const float* __restrict__ W0, const float* __restrict__ W1, const float* __restrict__ W2,
    u16* __restrict__ WT,
    const float* __restrict__ fu, const float* __restrict__ fi,
    u16* __restrict__ fb_u, u16* __restrict__ fb_i) {
  int bid = blockIdx.x;
  if (bid < 440) {                       // bucket histogram
    __shared__ int h[NB];
    for (int i = threadIdx.x; i < NB; i += 256) h[i] = 0;
    __syncthreads();
    int base = bid * CHUNK;
    for (int j = threadIdx.x; j < CHUNK; j += 256) {
      int e = base + j;
      if (e < ETOT) {
        int t = e / N_EDGE, i = e - t * N_EDGE;
        int d = (t == 0) ? duu[i] : ((t == 1) ? dub[i] : diu[i]);
        atomicAdd(&h[(t * N_USER + d) >> BSH], 1);
      }
    }
    __syncthreads();
    for (int i = threadIdx.x; i < NB; i += 256) if (h[i]) atomicAdd(&bhist[i], h[i]);
  } else if (bid < 443) {                // weight transpose + bf16 (stacked layout)
    int wsel = bid - 440;
    for (int idx = threadIdx.x; idx < D * D; idx += 256) {
      int n = idx >> 7, k = idx & 127;
      if (wsel == 0)      WT[n * 256 + k]       = f2b(W0[k * D + n]);   // W_uu -> WTu k<128
      else if (wsel == 1) WT[n * 256 + 128 + k] = f2b(W2[k * D + n]);   // W_iu -> WTu k>=128
      else                WT[32768 + n * D + k] = f2b(W1[k * D + n]);   // W_ub -> WTi
    }
  } else {                               // feature conversion, row-major
    int g = bid - 443;
    const float* src = fu; u16* dst = fb_u;
    if (g >= 6250) { g -= 6250; src = fi; dst = fb_i; }
    int gid = g * 256 + threadIdx.x;     // float4 groups: 1.6M per tensor
    float4 v = ((const float4*)src)[gid];
    union { u16 u[4]; uint2 d; } pk;
    pk.u[0] = f2b(v.x); pk.u[1] = f2b(v.y); pk.u[2] = f2b(v.z); pk.u[3] = f2b(v.w);
    ((uint2*)dst)[gid] = pk.d;
  }
}

// ---- place edges into bucket-grouped ebuf; each block re-derives the bucket scan
//      locally from bhist (replaces the k_bscan launch); block 0 publishes boff ----
__global__ void __launch_bounds__(256) k_bplace(
    const int* __restrict__ suu, const int* __restrict__ duu,
    const int* __restrict__ sub, const int* __restrict__ dub,
    const int* __restrict__ siu, const int* __restrict__ diu,
    const int* __restrict__ bhist, int* __restrict__ cursor,
    int* __restrict__ boff, u32* __restrict__ ebuf) {
  __shared__ int h[NB];
  __shared__ int sboff[NB];
  __shared__ int buf[256];
  int t = threadIdx.x;
  int v = (t < NB) ? bhist[t] : 0;
  buf[t] = v; __syncthreads();
  for (int s = 1; s < 256; s <<= 1) {
    int y = (t >= s) ? buf[t - s] : 0;
    __syncthreads(); buf[t] += y; __syncthreads();
  }
  if (t < NB) sboff[t] = (t == 0) ? 0 : buf[t - 1];
  if (blockIdx.x == 0 && t <= NB) boff[t] = (t == 0) ? 0 : buf[t - 1];
  for (int i = t; i < NB; i += 256) h[i] = 0;
  __syncthreads();
  int base = blockIdx.x * CHUNK;
  u32 pay[16], br[16];
#pragma unroll
  for (int k = 0; k < 16; ++k) {
    int e = base + k * 256 + t;
    br[k] = 0xFFFFFFFFu;
    if (e < ETOT) {
      int ty = e / N_EDGE, i = e - ty * N_EDGE;
      int d, s;
      if (ty == 0)      { d = duu[i]; s = suu[i]; }
      else if (ty == 1) { d = dub[i]; s = sub[i]; }
      else              { d = diu[i]; s = siu[i]; }
      int slot = ty * N_USER + d;
      int bu = slot >> BSH;
      int rank = atomicAdd(&h[bu], 1);
      pay[k] = (u32)s | ((u32)(slot & (SPAN - 1)) << 16);
      br[k]  = (u32)bu | ((u32)rank << 8);       // bu<=146 fits 8 bits; rank<4096
    }
  }
  __syncthreads();
  for (int i = t; i < NB; i += 256)
    h[i] = sboff[i] + atomicAdd(&cursor[i], h[i]);    // block base within bucket region
  __syncthreads();
#pragma unroll
  for (int k = 0; k < 16; ++k) {
    if (br[k] != 0xFFFFFFFFu) {
      int bu = br[k] & 0xFF, rank = (int)(br[k] >> 8);
      ebuf[h[bu] + rank] = pay[k];
    }
  }
}

// ---- per-bucket CSR finalize: off[] (coalesced) + ssrc[] (L2-local scatter) ----
__global__ void __launch_bounds__(256) k_csr(const int* __restrict__ boff, const u32* __restrict__ ebuf,
                                             int* __restrict__ off, u16* __restrict__ ssrc) {
  __shared__ int sc[SPAN];
  __shared__ int so[SPAN];
  __shared__ int part[256];
  int b = blockIdx.x;
  int ebase = boff[b], ecnt = boff[b + 1] - ebase;
  int sbase = b << BSH;
  int nslots = (NTOT - sbase < SPAN) ? (NTOT - sbase) : SPAN;
  for (int i = threadIdx.x; i < SPAN; i += 256) sc[i] = 0;
  __syncthreads();
  for (int j = threadIdx.x; j < ecnt; j += 256)
    atomicAdd(&sc[ebuf[ebase + j] >> 16], 1);
  __syncthreads();
  int t = threadIdx.x;
  int s0 = sc[4*t], s1 = sc[4*t+1], s2 = sc[4*t+2], s3 = sc[4*t+3];
  int tsum = s0 + s1 + s2 + s3;
  part[t] = tsum; __syncthreads();
  for (int s = 1; s < 256; s <<= 1) {
    int y = (t >= s) ? part[t - s] : 0;
    __syncthreads(); part[t] += y; __syncthreads();
  }
  int pbase = part[t] - tsum;
  so[4*t]   = pbase;
  so[4*t+1] = pbase + s0;
  so[4*t+2] = pbase + s0 + s1;
  so[4*t+3] = pbase + s0 + s1 + s2;
  __syncthreads();
  for (int i = threadIdx.x; i < nslots; i += 256)
    off[sbase + i] = ebase + so[i];
  if (b == 0 && threadIdx.x == 0) off[NTOT] = ETOT;
  for (int i = threadIdx.x; i < SPAN; i += 256) sc[i] = so[i];   // cursors
  __syncthreads();
  for (int j = threadIdx.x; j < ecnt; j += 256) {
    u32 p = ebuf[ebase + j];
    int pos = atomicAdd(&sc[p >> 16], 1);
    ssrc[ebase + pos] = (u16)(p & 0xFFFFu);
  }
}

// ---- gather-mean: HALF-wave (32 lanes) per slot, uint2 (8B) per lane per row,
//      4-edge unrolled for ILP. 2 slots/wave, 8 slots/block. Means -> d_out bf16. ----
__global__ void __launch_bounds__(256) k_mean(const u16* __restrict__ fb_u, const u16* __restrict__ fb_i,
                                              const int* __restrict__ off, const u16* __restrict__ ssrc,
                                              u16* __restrict__ ob) {
  int slot = blockIdx.x * 8 + (threadIdx.x >> 5);
  int lane = threadIdx.x & 31;
  if (slot >= NTOT) return;
  int t = slot / N_USER;
  int d = slot - t * N_USER;
  const u16* fb = (t == 2) ? fb_i : fb_u;
  int s = off[slot], e = off[slot + 1];
  float a0 = 0.f, a1 = 0.f, a2 = 0.f, a3 = 0.f;
  int i = s;
  for (; i + 4 <= e; i += 4) {
    int s0 = ssrc[i], s1 = ssrc[i + 1], s2 = ssrc[i + 2], s3 = ssrc[i + 3];
    uint2 v0 = ((const uint2*)(fb + (size_t)s0 * D))[lane];
    uint2 v1 = ((const uint2*)(fb + (size_t)s1 * D))[lane];
    uint2 v2 = ((const uint2*)(fb + (size_t)s2 * D))[lane];
    uint2 v3 = ((const uint2*)(fb + (size_t)s3 * D))[lane];
    a0 += blo2f(v0.x) + blo2f(v1.x) + blo2f(v2.x) + blo2f(v3.x);
    a1 += bhi2f(v0.x) + bhi2f(v1.x) + bhi2f(v2.x) + bhi2f(v3.x);
    a2 += blo2f(v0.y) + blo2f(v1.y) + blo2f(v2.y) + blo2f(v3.y);
    a3 += bhi2f(v0.y) + bhi2f(v1.y) + bhi2f(v2.y) + bhi2f(v3.y);
  }
  for (; i < e; ++i) {
    uint2 v = ((const uint2*)(fb + (size_t)ssrc[i] * D))[lane];
    a0 += blo2f(v.x); a1 += bhi2f(v.x);
    a2 += blo2f(v.y); a3 += bhi2f(v.y);
  }
  int n = e - s;
  float inv = (n > 0) ? 1.0f / (float)n : 0.f;
  u32 p0 = (u32)f2b(a0 * inv) | ((u32)f2b(a1 * inv) << 16);
  u32 p1 = (u32)f2b(a2 * inv) | ((u32)f2b(a3 * inv) << 16);
  u32* mrow;
  if (t == 0)      mrow = (u32*)(ob + (size_t)d * 256);              // mean_uu: row 1st half
  else if (t == 2) mrow = (u32*)(ob + (size_t)d * 256 + 128);        // mean_iu: row 2nd half
  else             mrow = (u32*)(ob + 12800000 + (size_t)d * 256);   // mean_ub: item row
  ((uint2*)mrow)[lane] = make_uint2(p0, p1);
}

// ---- final GEMM v2: no LDS, direct calibrated stores (m89: C/D col=lane&15,
//      row=(lane>>4)*4+reg), K=256 stacked user GEMM, 8 B-frags in flight per kk.
//      In-place on d_out: wave reads means of rows [row_base,row_base+16) and stores
//      f32 results to the same 16 rows (stores issue after MFMAs drained the reads). ----
__global__ void __launch_bounds__(256, 4) k_out(float* out, const u16* __restrict__ WT,
                                                const float* __restrict__ buu, const float* __restrict__ bub,
                                                const float* __restrict__ biu, const int* __restrict__ off) {
  int users = (blockIdx.y == 0);
  int tid = threadIdx.x;
  int w = tid >> 6, lane = tid & 63, quad = lane >> 4, l16 = lane & 15;
  int row_base = blockIdx.x * 64 + w * 16;      // this wave's 16-row tile
  int r0 = row_base + l16;
  int rA = r0 < N_USER ? r0 : N_USER - 1;
  const u16* ob = (const u16*)out;

  floatx4 acc[8];
#pragma unroll
  for (int i = 0; i < 8; i++) acc[i] = (floatx4){0.f, 0.f, 0.f, 0.f};

  if (users) {
    const u16* A = ob + (size_t)rA * 256 + quad * 8;          // [mean_uu|mean_iu] K=256
    const u16* B = WT + l16 * 256 + quad * 8;                 // WTu [n][k=256]
#pragma unroll
    for (int kk = 0; kk < 8; ++kk) {
      short8 af = *(const short8*)(A + kk * 32);
      short8 bf[8];
#pragma unroll
      for (int nt = 0; nt < 8; ++nt)
        bf[nt] = *(const short8*)(B + nt * 4096 + kk * 32);   // 8 independent loads
#pragma unroll
      for (int nt = 0; nt < 8; ++nt)
        acc[nt] = __builtin_amdgcn_mfma_f32_16x16x32_bf16(af, bf[nt], acc[nt], 0, 0, 0);
    }
  } else {
    const u16* A = ob + 12800000 + (size_t)rA * 256 + quad * 8;  // mean_ub K=128
    const u16* B = WT + 32768 + l16 * 128 + quad * 8;            // WTi [n][k=128]
#pragma unroll
    for (int kk = 0; kk < 4; ++kk) {
      short8 af = *(const short8*)(A + kk * 32);
      short8 bf[8];
#pragma unroll
      for (int nt = 0; nt < 8; ++nt)
        bf[nt] = *(const short8*)(B + nt * 2048 + kk * 32);
#pragma unroll
      for (int nt = 0; nt < 8; ++nt)
        acc[nt] = __builtin_amdgcn_mfma_f32_16x16x32_bf16(af, bf[nt], acc[nt], 0, 0, 0);
    }
  }

  // degree gates for this lane's 4 output rows (row = quad*4 + i within the tile)
  int nA[4], nB[4];
#pragma unroll
  for (int i = 0; i < 4; ++i) {
    int grow = row_base + quad * 4 + i;
    bool ok = grow < N_USER;
    if (users) {
      nA[i] = ok ? (off[grow + 1] - off[grow]) : 0;                             // uu
      nB[i] = ok ? (off[2 * N_USER + grow + 1] - off[2 * N_USER + grow]) : 0;   // iu
    } else {
      nA[i] = ok ? (off[N_USER + grow + 1] - off[N_USER + grow]) : 0;           // ub
      nB[i] = 0;
    }
  }

#pragma unroll
  for (int nt = 0; nt < 8; ++nt) {
    int col = nt * 16 + l16;
    float bA = users ? buu[col] : bub[col];
    float bB = users ? biu[col] : 0.f;
#pragma unroll
    for (int i = 0; i < 4; ++i) {
      int grow = row_base + quad * 4 + i;
      if (grow < N_USER) {
        float r = acc[nt][i] + (nA[i] > 0 ? bA : 0.f) + (nB[i] > 0 ? bB : 0.f);
        out[(size_t)(users ? grow : N_USER + grow) * D + col] = r;
      }
    }
  }
}

extern "C" void kernel_launch(void* const* d_in, const int* in_sizes, int n_in,
                              void* d_out, int out_size, void* d_ws, size_t ws_size,
                              hipStream_t stream) {
  const float* fu  = (const float*)d_in[0];
  const float* fi  = (const float*)d_in[1];
  const float* Wuu = (const float*)d_in[2];
  const float* buu = (const float*)d_in[3];
  const float* Wub = (const float*)d_in[4];
  const float* bub = (const float*)d_in[5];
  const float* Wiu = (const float*)d_in[6];
  const float* biu = (const float*)d_in[7];
  const int* suu = (const int*)d_in[8];
  const int* duu = (const int*)d_in[9];
  const int* sub = (const int*)d_in[10];
  const int* dub = (const int*)d_in[11];
  const int* siu = (const int*)d_in[12];
  const int* diu = (const int*)d_in[13];
  float* out = (float*)d_out;   // f32: [out_user 50000x128 | out_item 50000x128]
  u16* ob = (u16*)d_out;
  // d_out scratch (race-free): k_mean writes bf16 means INTO the output rows
  //   user row r: [0,256B)=mean_uu, [256B,512B)=mean_iu ; item row r: [0,256B)=mean_ub
  // k_out waves read only their own 16 rows' means, then overwrite those rows.

  // workspace layout (37.1 MB), offsets in INTs (verified r3):
  //   WT = 49,152 u16 = 24,576 ints; fb_u = 6,400,000 u16 = 3,200,000 ints
  int* wsi    = (int*)d_ws;
  int* off    = wsi;                        // [150001] -> pad to 150016
  int* bhist  = wsi + 150016;               // [147]
  int* cursor = wsi + 150208;               // [147]
  int* boff   = wsi + 150400;               // [148]
  u32* ebuf   = (u32*)(wsi + 150592);       // [1800000] (7.2 MB)
  u16* ssrc   = (u16*)(wsi + 1950592);      // [1800000] u16 (3.6 MB)
  u16* WT     = (u16*)(wsi + 2850592);      // WTu 32768 + WTi 16384 u16 (96 KB)
  u16* fb_u   = (u16*)(wsi + 2875168);      // 50000x128 bf16 row-major (12.8 MB)
  u16* fb_i   = (u16*)(wsi + 6075168);      // 50000x128 bf16 row-major (12.8 MB)

  hipMemsetAsync(bhist, 0, 384 * sizeof(int), stream);   // bhist + cursor
  k_front<<<443 + 12500, 256, 0, stream>>>(duu, dub, diu, bhist, Wuu, Wub, Wiu, WT,
                                           fu, fi, fb_u, fb_i);
  k_bplace<<<440, 256, 0, stream>>>(suu, duu, sub, dub, siu, diu, bhist, cursor, boff, ebuf);
  k_csr<<<NB, 256, 0, stream>>>(boff, ebuf, off, ssrc);
  k_mean<<<18750, 256, 0, stream>>>(fb_u, fb_i, off, ssrc, ob);
  k_out<<<dim3(782, 2), 256, 0, stream>>>(out, WT, buu, bub, biu, off);
}

// Round 7
// 303.800 us; speedup vs baseline: 1.5976x; 1.0302x over previous
//
#include <hip/hip_runtime.h>
#include <stdint.h>
#include <string.h>

#define N_USER 50000
#define N_ITEM 50000
#define N_EDGE 600000
#define D 128
#define NTOT 150000      // 3 * 50000 destination slots (uu | ub | iu)
#define ETOT 1800000
#define NB 147           // buckets = ceil(NTOT / SPAN)
#define BSH 10
#define SPAN 1024        // slots per bucket
#define CHUNK 4096       // edges per block in bucket kernels (16/thread)

typedef unsigned short u16;
typedef unsigned int   u32;
typedef __attribute__((ext_vector_type(8))) short short8;   // 8 bf16 (MFMA A/B frag)
typedef __attribute__((ext_vector_type(4))) float floatx4;  // MFMA C/D frag

static __device__ __forceinline__ u16 f2b(float f) {        // f32 -> bf16 RNE
  u32 x; memcpy(&x, &f, 4);
  u32 r = x + 0x7fffu + ((x >> 16) & 1u);
  return (u16)(r >> 16);
}
static __device__ __forceinline__ float blo2f(u32 v) {
  u32 x = v << 16; float f; memcpy(&f, &x, 4); return f;
}
static __device__ __forceinline__ float bhi2f(u32 v) {
  u32 x = v & 0xffff0000u; float f; memcpy(&f, &x, 4); return f;
}

// ---- front: [0,440) edge-bucket histogram | [440,443) weight transpose (stacked) |
//      rest: f32->bf16 feature conversion into ROW-MAJOR bf16 tables ----
// WTu = [W_uu ; W_iu]^T as [n=128][k=256] (user GEMM is K=256 over [mean_uu|mean_iu]).
// WTi = W_ub^T as [n=128][k=128], at WT + 32768 u16.
__global__ void __launch_bounds__(256) k_front(
    const int* __restrict__ duu, const int* __restrict__ dub, const int* __restrict__ diu,
    int* __restrict__ bhist,
    const float* __restrict__ W0, const float* __restrict__ W1, const float* __restrict__ W2,
    u16* __restrict__ WT,
    const float* __restrict__ fu, const float* __restrict__ fi,
    u16* __restrict__ fb_u, u16* __restrict__ fb_i) {
  int bid = blockIdx.x;
  if (bid < 440) {                       // bucket histogram
    __shared__ int h[NB];
    for (int i = threadIdx.x; i < NB; i += 256) h[i] = 0;
    __syncthreads();
    int base = bid * CHUNK;
    for (int j = threadIdx.x; j < CHUNK; j += 256) {
      int e = base + j;
      if (e < ETOT) {
        int t = e / N_EDGE, i = e - t * N_EDGE;
        int d = (t == 0) ? duu[i] : ((t == 1) ? dub[i] : diu[i]);
        atomicAdd(&h[(t * N_USER + d) >> BSH], 1);
      }
    }
    __syncthreads();
    for (int i = threadIdx.x; i < NB; i += 256) if (h[i]) atomicAdd(&bhist[i], h[i]);
  } else if (bid < 443) {                // weight transpose + bf16 (stacked layout)
    int wsel = bid - 440;
    for (int idx = threadIdx.x; idx < D * D; idx += 256) {
      int n = idx >> 7, k = idx & 127;
      if (wsel == 0)      WT[n * 256 + k]       = f2b(W0[k * D + n]);   // W_uu -> WTu k<128
      else if (wsel == 1) WT[n * 256 + 128 + k] = f2b(W2[k * D + n]);   // W_iu -> WTu k>=128
      else                WT[32768 + n * D + k] = f2b(W1[k * D + n]);   // W_ub -> WTi
    }
  } else {                               // feature conversion, row-major
    int g = bid - 443;
    const float* src = fu; u16* dst = fb_u;
    if (g >= 6250) { g -= 6250; src = fi; dst = fb_i; }
    int gid = g * 256 + threadIdx.x;     // float4 groups: 1.6M per tensor
    float4 v = ((const float4*)src)[gid];
    union { u16 u[4]; uint2 d; } pk;
    pk.u[0] = f2b(v.x); pk.u[1] = f2b(v.y); pk.u[2] = f2b(v.z); pk.u[3] = f2b(v.w);
    ((uint2*)dst)[gid] = pk.d;
  }
}

// ---- place edges into bucket-grouped ebuf; each block re-derives the bucket scan
//      locally from bhist (replaces the k_bscan launch); block 0 publishes boff ----
__global__ void __launch_bounds__(256) k_bplace(
    const int* __restrict__ suu, const int* __restrict__ duu,
    const int* __restrict__ sub, const int* __restrict__ dub,
    const int* __restrict__ siu, const int* __restrict__ diu,
    const int* __restrict__ bhist, int* __restrict__ cursor,
    int* __restrict__ boff, u32* __restrict__ ebuf) {
  __shared__ int h[NB];
  __shared__ int sboff[NB];
  __shared__ int buf[256];
  int t = threadIdx.x;
  int v = (t < NB) ? bhist[t] : 0;
  buf[t] = v; __syncthreads();
  for (int s = 1; s < 256; s <<= 1) {
    int y = (t >= s) ? buf[t - s] : 0;
    __syncthreads(); buf[t] += y; __syncthreads();
  }
  if (t < NB) sboff[t] = (t == 0) ? 0 : buf[t - 1];
  if (blockIdx.x == 0 && t <= NB) boff[t] = (t == 0) ? 0 : buf[t - 1];
  for (int i = t; i < NB; i += 256) h[i] = 0;
  __syncthreads();
  int base = blockIdx.x * CHUNK;
  u32 pay[16], br[16];
#pragma unroll
  for (int k = 0; k < 16; ++k) {
    int e = base + k * 256 + t;
    br[k] = 0xFFFFFFFFu;
    if (e < ETOT) {
      int ty = e / N_EDGE, i = e - ty * N_EDGE;
      int d, s;
      if (ty == 0)      { d = duu[i]; s = suu[i]; }
      else if (ty == 1) { d = dub[i]; s = sub[i]; }
      else              { d = diu[i]; s = siu[i]; }
      int slot = ty * N_USER + d;
      int bu = slot >> BSH;
      int rank = atomicAdd(&h[bu], 1);
      pay[k] = (u32)s | ((u32)(slot & (SPAN - 1)) << 16);
      br[k]  = (u32)bu | ((u32)rank << 8);       // bu<=146 fits 8 bits; rank<4096
    }
  }
  __syncthreads();
  for (int i = t; i < NB; i += 256)
    h[i] = sboff[i] + atomicAdd(&cursor[i], h[i]);    // block base within bucket region
  __syncthreads();
#pragma unroll
  for (int k = 0; k < 16; ++k) {
    if (br[k] != 0xFFFFFFFFu) {
      int bu = br[k] & 0xFF, rank = (int)(br[k] >> 8);
      ebuf[h[bu] + rank] = pay[k];
    }
  }
}

// ---- per-bucket CSR finalize: off[] (coalesced) + ssrc[] (L2-local scatter) ----
__global__ void __launch_bounds__(256) k_csr(const int* __restrict__ boff, const u32* __restrict__ ebuf,
                                             int* __restrict__ off, u16* __restrict__ ssrc) {
  __shared__ int sc[SPAN];
  __shared__ int so[SPAN];
  __shared__ int part[256];
  int b = blockIdx.x;
  int ebase = boff[b], ecnt = boff[b + 1] - ebase;
  int sbase = b << BSH;
  int nslots = (NTOT - sbase < SPAN) ? (NTOT - sbase) : SPAN;
  for (int i = threadIdx.x; i < SPAN; i += 256) sc[i] = 0;
  __syncthreads();
  for (int j = threadIdx.x; j < ecnt; j += 256)
    atomicAdd(&sc[ebuf[ebase + j] >> 16], 1);
  __syncthreads();
  int t = threadIdx.x;
  int s0 = sc[4*t], s1 = sc[4*t+1], s2 = sc[4*t+2], s3 = sc[4*t+3];
  int tsum = s0 + s1 + s2 + s3;
  part[t] = tsum; __syncthreads();
  for (int s = 1; s < 256; s <<= 1) {
    int y = (t >= s) ? part[t - s] : 0;
    __syncthreads(); part[t] += y; __syncthreads();
  }
  int pbase = part[t] - tsum;
  so[4*t]   = pbase;
  so[4*t+1] = pbase + s0;
  so[4*t+2] = pbase + s0 + s1;
  so[4*t+3] = pbase + s0 + s1 + s2;
  __syncthreads();
  for (int i = threadIdx.x; i < nslots; i += 256)
    off[sbase + i] = ebase + so[i];
  if (b == 0 && threadIdx.x == 0) off[NTOT] = ETOT;
  for (int i = threadIdx.x; i < SPAN; i += 256) sc[i] = so[i];   // cursors
  __syncthreads();
  for (int j = threadIdx.x; j < ecnt; j += 256) {
    u32 p = ebuf[ebase + j];
    int pos = atomicAdd(&sc[p >> 16], 1);
    ssrc[ebase + pos] = (u16)(p & 0xFFFFu);
  }
}

// ---- gather-mean v3: HALF-wave (32 lanes) per slot, uint2 (8B) per lane per row.
//      Edge indices PRELOADED once (lane j holds ssrc[s+j], one coalesced VMEM op)
//      and broadcast per-edge via __shfl(.,e,32) on the idle LDS pipe -- removes the
//      dependent ssrc->row VMEM chain. Degree>32 falls back to direct loads. ----
__global__ void __launch_bounds__(256) k_mean(const u16* __restrict__ fb_u, const u16* __restrict__ fb_i,
                                              const int* __restrict__ off, const u16* __restrict__ ssrc,
                                              u16* __restrict__ ob) {
  int slot = blockIdx.x * 8 + (threadIdx.x >> 5);
  int lane = threadIdx.x & 31;
  if (slot >= NTOT) return;
  int t = slot / N_USER;
  int d = slot - t * N_USER;
  const u16* fb = (t == 2) ? fb_i : fb_u;
  int s = off[slot], e = off[slot + 1];
  int n = e - s;
  int my_src = (lane < n) ? (int)ssrc[s + lane] : 0;   // preload up to 32 edge srcs
  float a0 = 0.f, a1 = 0.f, a2 = 0.f, a3 = 0.f;
  int m = (n < 32) ? n : 32;
  int i = 0;
  for (; i + 4 <= m; i += 4) {
    int s0 = __shfl(my_src, i, 32);
    int s1 = __shfl(my_src, i + 1, 32);
    int s2 = __shfl(my_src, i + 2, 32);
    int s3 = __shfl(my_src, i + 3, 32);
    uint2 v0 = ((const uint2*)(fb + (size_t)s0 * D))[lane];
    uint2 v1 = ((const uint2*)(fb + (size_t)s1 * D))[lane];
    uint2 v2 = ((const uint2*)(fb + (size_t)s2 * D))[lane];
    uint2 v3 = ((const uint2*)(fb + (size_t)s3 * D))[lane];
    a0 += blo2f(v0.x) + blo2f(v1.x) + blo2f(v2.x) + blo2f(v3.x);
    a1 += bhi2f(v0.x) + bhi2f(v1.x) + bhi2f(v2.x) + bhi2f(v3.x);
    a2 += blo2f(v0.y) + blo2f(v1.y) + blo2f(v2.y) + blo2f(v3.y);
    a3 += bhi2f(v0.y) + bhi2f(v1.y) + bhi2f(v2.y) + bhi2f(v3.y);
  }
  for (; i < m; ++i) {
    int sr = __shfl(my_src, i, 32);
    uint2 v = ((const uint2*)(fb + (size_t)sr * D))[lane];
    a0 += blo2f(v.x); a1 += bhi2f(v.x);
    a2 += blo2f(v.y); a3 += bhi2f(v.y);
  }
  for (int j = s + 32; j < e; ++j) {     // rare degree>32 remainder
    int sr = ssrc[j];
    uint2 v = ((const uint2*)(fb + (size_t)sr * D))[lane];
    a0 += blo2f(v.x); a1 += bhi2f(v.x);
    a2 += blo2f(v.y); a3 += bhi2f(v.y);
  }
  float inv = (n > 0) ? 1.0f / (float)n : 0.f;
  u32 p0 = (u32)f2b(a0 * inv) | ((u32)f2b(a1 * inv) << 16);
  u32 p1 = (u32)f2b(a2 * inv) | ((u32)f2b(a3 * inv) << 16);
  u32* mrow;
  if (t == 0)      mrow = (u32*)(ob + (size_t)d * 256);              // mean_uu: row 1st half
  else if (t == 2) mrow = (u32*)(ob + (size_t)d * 256 + 128);        // mean_iu: row 2nd half
  else             mrow = (u32*)(ob + 12800000 + (size_t)d * 256);   // mean_ub: item row
  ((uint2*)mrow)[lane] = make_uint2(p0, p1);
}

// ---- final GEMM v2: no LDS, direct calibrated stores (m89: C/D col=lane&15,
//      row=(lane>>4)*4+reg), K=256 stacked user GEMM, 8 B-frags in flight per kk.
//      In-place on d_out: wave reads means of rows [row_base,row_base+16) and stores
//      f32 results to the same 16 rows (stores issue after MFMAs drained the reads). ----
__global__ void __launch_bounds__(256, 4) k_out(float* out, const u16* __restrict__ WT,
                                                const float* __restrict__ buu, const float* __restrict__ bub,
                                                const float* __restrict__ biu, const int* __restrict__ off) {
  int users = (blockIdx.y == 0);
  int tid = threadIdx.x;
  int w = tid >> 6, lane = tid & 63, quad = lane >> 4, l16 = lane & 15;
  int row_base = blockIdx.x * 64 + w * 16;      // this wave's 16-row tile
  int r0 = row_base + l16;
  int rA = r0 < N_USER ? r0 : N_USER - 1;
  const u16* ob = (const u16*)out;

  floatx4 acc[8];
#pragma unroll
  for (int i = 0; i < 8; i++) acc[i] = (floatx4){0.f, 0.f, 0.f, 0.f};

  if (users) {
    const u16* A = ob + (size_t)rA * 256 + quad * 8;          // [mean_uu|mean_iu] K=256
    const u16* B = WT + l16 * 256 + quad * 8;                 // WTu [n][k=256]
#pragma unroll
    for (int kk = 0; kk < 8; ++kk) {
      short8 af = *(const short8*)(A + kk * 32);
      short8 bf[8];
#pragma unroll
      for (int nt = 0; nt < 8; ++nt)
        bf[nt] = *(const short8*)(B + nt * 4096 + kk * 32);   // 8 independent loads
#pragma unroll
      for (int nt = 0; nt < 8; ++nt)
        acc[nt] = __builtin_amdgcn_mfma_f32_16x16x32_bf16(af, bf[nt], acc[nt], 0, 0, 0);
    }
  } else {
    const u16* A = ob + 12800000 + (size_t)rA * 256 + quad * 8;  // mean_ub K=128
    const u16* B = WT + 32768 + l16 * 128 + quad * 8;            // WTi [n][k=128]
#pragma unroll
    for (int kk = 0; kk < 4; ++kk) {
      short8 af = *(const short8*)(A + kk * 32);
      short8 bf[8];
#pragma unroll
      for (int nt = 0; nt < 8; ++nt)
        bf[nt] = *(const short8*)(B + nt * 2048 + kk * 32);
#pragma unroll
      for (int nt = 0; nt < 8; ++nt)
        acc[nt] = __builtin_amdgcn_mfma_f32_16x16x32_bf16(af, bf[nt], acc[nt], 0, 0, 0);
    }
  }

  // degree gates for this lane's 4 output rows (row = quad*4 + i within the tile)
  int nA[4], nB[4];
#pragma unroll
  for (int i = 0; i < 4; ++i) {
    int grow = row_base + quad * 4 + i;
    bool ok = grow < N_USER;
    if (users) {
      nA[i] = ok ? (off[grow + 1] - off[grow]) : 0;                             // uu
      nB[i] = ok ? (off[2 * N_USER + grow + 1] - off[2 * N_USER + grow]) : 0;   // iu
    } else {
      nA[i] = ok ? (off[N_USER + grow + 1] - off[N_USER + grow]) : 0;           // ub
      nB[i] = 0;
    }
  }

#pragma unroll
  for (int nt = 0; nt < 8; ++nt) {
    int col = nt * 16 + l16;
    float bA = users ? buu[col] : bub[col];
    float bB = users ? biu[col] : 0.f;
#pragma unroll
    for (int i = 0; i < 4; ++i) {
      int grow = row_base + quad * 4 + i;
      if (grow < N_USER) {
        float r = acc[nt][i] + (nA[i] > 0 ? bA : 0.f) + (nB[i] > 0 ? bB : 0.f);
        out[(size_t)(users ? grow : N_USER + grow) * D + col] = r;
      }
    }
  }
}

extern "C" void kernel_launch(void* const* d_in, const int* in_sizes, int n_in,
                              void* d_out, int out_size, void* d_ws, size_t ws_size,
                              hipStream_t stream) {
  const float* fu  = (const float*)d_in[0];
  const float* fi  = (const float*)d_in[1];
  const float* Wuu = (const float*)d_in[2];
  const float* buu = (const float*)d_in[3];
  const float* Wub = (const float*)d_in[4];
  const float* bub = (const float*)d_in[5];
  const float* Wiu = (const float*)d_in[6];
  const float* biu = (const float*)d_in[7];
  const int* suu = (const int*)d_in[8];
  const int* duu = (const int*)d_in[9];
  const int* sub = (const int*)d_in[10];
  const int* dub = (const int*)d_in[11];
  const int* siu = (const int*)d_in[12];
  const int* diu = (const int*)d_in[13];
  float* out = (float*)d_out;   // f32: [out_user 50000x128 | out_item 50000x128]
  u16* ob = (u16*)d_out;
  // d_out scratch (race-free): k_mean writes bf16 means INTO the output rows
  //   user row r: [0,256B)=mean_uu, [256B,512B)=mean_iu ; item row r: [0,256B)=mean_ub
  // k_out waves read only their own 16 rows' means, then overwrite those rows.

  // workspace layout (37.1 MB), offsets in INTs (verified r3):
  //   WT = 49,152 u16 = 24,576 ints; fb_u = 6,400,000 u16 = 3,200,000 ints
  int* wsi    = (int*)d_ws;
  int* off    = wsi;                        // [150001] -> pad to 150016
  int* bhist  = wsi + 150016;               // [147]
  int* cursor = wsi + 150208;               // [147]
  int* boff   = wsi + 150400;               // [148]
  u32* ebuf   = (u32*)(wsi + 150592);       // [1800000] (7.2 MB)
  u16* ssrc   = (u16*)(wsi + 1950592);      // [1800000] u16 (3.6 MB)
  u16* WT     = (u16*)(wsi + 2850592);      // WTu 32768 + WTi 16384 u16 (96 KB)
  u16* fb_u   = (u16*)(wsi + 2875168);      // 50000x128 bf16 row-major (12.8 MB)
  u16* fb_i   = (u16*)(wsi + 6075168);      // 50000x128 bf16 row-major (12.8 MB)

  hipMemsetAsync(bhist, 0, 384 * sizeof(int), stream);   // bhist + cursor
  k_front<<<443 + 12500, 256, 0, stream>>>(duu, dub, diu, bhist, Wuu, Wub, Wiu, WT,
                                           fu, fi, fb_u, fb_i);
  k_bplace<<<440, 256, 0, stream>>>(suu, duu, sub, dub, siu, diu, bhist, cursor, boff, ebuf);
  k_csr<<<NB, 256, 0, stream>>>(boff, ebuf, off, ssrc);
  k_mean<<<18750, 256, 0, stream>>>(fb_u, fb_i, off, ssrc, ob);
  k_out<<<dim3(782, 2), 256, 0, stream>>>(out, WT, buu, bub, biu, off);
}

// Round 8
// 286.415 us; speedup vs baseline: 1.6946x; 1.0607x over previous
//
#include <hip/hip_runtime.h>
#include <stdint.h>
#include <string.h>

#define N_USER 50000
#define N_ITEM 50000
#define N_EDGE 600000
#define D 128
#define NTOT 150000      // 3 * 50000 destination slots (uu | ub | iu)
#define ETOT 1800000
#define NB 147           // buckets = ceil(NTOT / SPAN)
#define BSH 10
#define SPAN 1024        // slots per bucket
#define CHUNK 4096       // edges per block in bucket kernels (16/thread)

typedef unsigned short u16;
typedef unsigned int   u32;
typedef __attribute__((ext_vector_type(8))) short short8;   // 8 bf16 (MFMA A/B frag)
typedef __attribute__((ext_vector_type(4))) float floatx4;  // MFMA C/D frag

static __device__ __forceinline__ u16 f2b(float f) {        // f32 -> bf16 RNE
  u32 x; memcpy(&x, &f, 4);
  u32 r = x + 0x7fffu + ((x >> 16) & 1u);
  return (u16)(r >> 16);
}
static __device__ __forceinline__ float blo2f(u32 v) {
  u32 x = v << 16; float f; memcpy(&f, &x, 4); return f;
}
static __device__ __forceinline__ float bhi2f(u32 v) {
  u32 x = v & 0xffff0000u; float f; memcpy(&f, &x, 4); return f;
}

// ---- front: [0,440) edge-bucket histogram | [440,443) weight transpose (stacked) |
//      rest: f32->bf16 feature conversion into ROW-MAJOR bf16 tables ----
// WTu = [W_uu ; W_iu]^T as [n=128][k=256] (user GEMM is K=256 over [mean_uu|mean_iu]).
// WTi = W_ub^T as [n=128][k=128], at WT + 32768 u16.
__global__ void __launch_bounds__(256) k_front(
    const int* __restrict__ duu, const int* __restrict__ dub, const int* __restrict__ diu,
    int* __restrict__ bhist,
    const float* __restrict__ W0, const float* __restrict__ W1, const float* __restrict__ W2,
    u16* __restrict__ WT,
    const float* __restrict__ fu, const float* __restrict__ fi,
    u16* __restrict__ fb_u, u16* __restrict__ fb_i) {
  int bid = blockIdx.x;
  if (bid < 440) {                       // bucket histogram
    __shared__ int h[NB];
    for (int i = threadIdx.x; i < NB; i += 256) h[i] = 0;
    __syncthreads();
    int base = bid * CHUNK;
    for (int j = threadIdx.x; j < CHUNK; j += 256) {
      int e = base + j;
      if (e < ETOT) {
        int t = e / N_EDGE, i = e - t * N_EDGE;
        int d = (t == 0) ? duu[i] : ((t == 1) ? dub[i] : diu[i]);
        atomicAdd(&h[(t * N_USER + d) >> BSH], 1);
      }
    }
    __syncthreads();
    for (int i = threadIdx.x; i < NB; i += 256) if (h[i]) atomicAdd(&bhist[i], h[i]);
  } else if (bid < 443) {                // weight transpose + bf16 (stacked layout)
    int wsel = bid - 440;
    for (int idx = threadIdx.x; idx < D * D; idx += 256) {
      int n = idx >> 7, k = idx & 127;
      if (wsel == 0)      WT[n * 256 + k]       = f2b(W0[k * D + n]);   // W_uu -> WTu k<128
      else if (wsel == 1) WT[n * 256 + 128 + k] = f2b(W2[k * D + n]);   // W_iu -> WTu k>=128
      else                WT[32768 + n * D + k] = f2b(W1[k * D + n]);   // W_ub -> WTi
    }
  } else {                               // feature conversion, row-major
    int g = bid - 443;
    const float* src = fu; u16* dst = fb_u;
    if (g >= 6250) { g -= 6250; src = fi; dst = fb_i; }
    int gid = g * 256 + threadIdx.x;     // float4 groups: 1.6M per tensor
    float4 v = ((const float4*)src)[gid];
    union { u16 u[4]; uint2 d; } pk;
    pk.u[0] = f2b(v.x); pk.u[1] = f2b(v.y); pk.u[2] = f2b(v.z); pk.u[3] = f2b(v.w);
    ((uint2*)dst)[gid] = pk.d;
  }
}

// ---- place edges into bucket-grouped ebuf; each block re-derives the bucket scan
//      locally from bhist (replaces the k_bscan launch); block 0 publishes boff ----
__global__ void __launch_bounds__(256) k_bplace(
    const int* __restrict__ suu, const int* __restrict__ duu,
    const int* __restrict__ sub, const int* __restrict__ dub,
    const int* __restrict__ siu, const int* __restrict__ diu,
    const int* __restrict__ bhist, int* __restrict__ cursor,
    int* __restrict__ boff, u32* __restrict__ ebuf) {
  __shared__ int h[NB];
  __shared__ int sboff[NB];
  __shared__ int buf[256];
  int t = threadIdx.x;
  int v = (t < NB) ? bhist[t] : 0;
  buf[t] = v; __syncthreads();
  for (int s = 1; s < 256; s <<= 1) {
    int y = (t >= s) ? buf[t - s] : 0;
    __syncthreads(); buf[t] += y; __syncthreads();
  }
  if (t < NB) sboff[t] = (t == 0) ? 0 : buf[t - 1];
  if (blockIdx.x == 0 && t <= NB) boff[t] = (t == 0) ? 0 : buf[t - 1];
  for (int i = t; i < NB; i += 256) h[i] = 0;
  __syncthreads();
  int base = blockIdx.x * CHUNK;
  u32 pay[16], br[16];
#pragma unroll
  for (int k = 0; k < 16; ++k) {
    int e = base + k * 256 + t;
    br[k] = 0xFFFFFFFFu;
    if (e < ETOT) {
      int ty = e / N_EDGE, i = e - ty * N_EDGE;
      int d, s;
      if (ty == 0)      { d = duu[i]; s = suu[i]; }
      else if (ty == 1) { d = dub[i]; s = sub[i]; }
      else              { d = diu[i]; s = siu[i]; }
      int slot = ty * N_USER + d;
      int bu = slot >> BSH;
      int rank = atomicAdd(&h[bu], 1);
      pay[k] = (u32)s | ((u32)(slot & (SPAN - 1)) << 16);
      br[k]  = (u32)bu | ((u32)rank << 8);       // bu<=146 fits 8 bits; rank<4096
    }
  }
  __syncthreads();
  for (int i = t; i < NB; i += 256)
    h[i] = sboff[i] + atomicAdd(&cursor[i], h[i]);    // block base within bucket region
  __syncthreads();
#pragma unroll
  for (int k = 0; k < 16; ++k) {
    if (br[k] != 0xFFFFFFFFu) {
      int bu = br[k] & 0xFF, rank = (int)(br[k] >> 8);
      ebuf[h[bu] + rank] = pay[k];
    }
  }
}

// ---- per-bucket CSR finalize: off[] (coalesced) + ssrc[] (L2-local scatter) ----
__global__ void __launch_bounds__(256) k_csr(const int* __restrict__ boff, const u32* __restrict__ ebuf,
                                             int* __restrict__ off, u16* __restrict__ ssrc) {
  __shared__ int sc[SPAN];
  __shared__ int so[SPAN];
  __shared__ int part[256];
  int b = blockIdx.x;
  int ebase = boff[b], ecnt = boff[b + 1] - ebase;
  int sbase = b << BSH;
  int nslots = (NTOT - sbase < SPAN) ? (NTOT - sbase) : SPAN;
  for (int i = threadIdx.x; i < SPAN; i += 256) sc[i] = 0;
  __syncthreads();
  for (int j = threadIdx.x; j < ecnt; j += 256)
    atomicAdd(&sc[ebuf[ebase + j] >> 16], 1);
  __syncthreads();
  int t = threadIdx.x;
  int s0 = sc[4*t], s1 = sc[4*t+1], s2 = sc[4*t+2], s3 = sc[4*t+3];
  int tsum = s0 + s1 + s2 + s3;
  part[t] = tsum; __syncthreads();
  for (int s = 1; s < 256; s <<= 1) {
    int y = (t >= s) ? part[t - s] : 0;
    __syncthreads(); part[t] += y; __syncthreads();
  }
  int pbase = part[t] - tsum;
  so[4*t]   = pbase;
  so[4*t+1] = pbase + s0;
  so[4*t+2] = pbase + s0 + s1;
  so[4*t+3] = pbase + s0 + s1 + s2;
  __syncthreads();
  for (int i = threadIdx.x; i < nslots; i += 256)
    off[sbase + i] = ebase + so[i];
  if (b == 0 && threadIdx.x == 0) off[NTOT] = ETOT;
  for (int i = threadIdx.x; i < SPAN; i += 256) sc[i] = so[i];   // cursors
  __syncthreads();
  for (int j = threadIdx.x; j < ecnt; j += 256) {
    u32 p = ebuf[ebase + j];
    int pos = atomicAdd(&sc[p >> 16], 1);
    ssrc[ebase + pos] = (u16)(p & 0xFFFFu);
  }
}

// ---- gather-mean v3: HALF-wave (32 lanes) per slot, uint2 (8B) per lane per row.
//      Edge indices PRELOADED once (lane j holds ssrc[s+j], one coalesced VMEM op)
//      and broadcast per-edge via __shfl(.,e,32) on the idle LDS pipe -- removes the
//      dependent ssrc->row VMEM chain. Degree>32 falls back to direct loads. ----
__global__ void __launch_bounds__(256) k_mean(const u16* __restrict__ fb_u, const u16* __restrict__ fb_i,
                                              const int* __restrict__ off, const u16* __restrict__ ssrc,
                                              u16* __restrict__ ob) {
  int slot = blockIdx.x * 8 + (threadIdx.x >> 5);
  int lane = threadIdx.x & 31;
  if (slot >= NTOT) return;
  int t = slot / N_USER;
  int d = slot - t * N_USER;
  const u16* fb = (t == 2) ? fb_i : fb_u;
  int s = off[slot], e = off[slot + 1];
  int n = e - s;
  int my_src = (lane < n) ? (int)ssrc[s + lane] : 0;   // preload up to 32 edge srcs
  float a0 = 0.f, a1 = 0.f, a2 = 0.f, a3 = 0.f;
  int m = (n < 32) ? n : 32;
  int i = 0;
  for (; i + 4 <= m; i += 4) {
    int s0 = __shfl(my_src, i, 32);
    int s1 = __shfl(my_src, i + 1, 32);
    int s2 = __shfl(my_src, i + 2, 32);
    int s3 = __shfl(my_src, i + 3, 32);
    uint2 v0 = ((const uint2*)(fb + (size_t)s0 * D))[lane];
    uint2 v1 = ((const uint2*)(fb + (size_t)s1 * D))[lane];
    uint2 v2 = ((const uint2*)(fb + (size_t)s2 * D))[lane];
    uint2 v3 = ((const uint2*)(fb + (size_t)s3 * D))[lane];
    a0 += blo2f(v0.x) + blo2f(v1.x) + blo2f(v2.x) + blo2f(v3.x);
    a1 += bhi2f(v0.x) + bhi2f(v1.x) + bhi2f(v2.x) + bhi2f(v3.x);
    a2 += blo2f(v0.y) + blo2f(v1.y) + blo2f(v2.y) + blo2f(v3.y);
    a3 += bhi2f(v0.y) + bhi2f(v1.y) + bhi2f(v2.y) + bhi2f(v3.y);
  }
  for (; i < m; ++i) {
    int sr = __shfl(my_src, i, 32);
    uint2 v = ((const uint2*)(fb + (size_t)sr * D))[lane];
    a0 += blo2f(v.x); a1 += bhi2f(v.x);
    a2 += blo2f(v.y); a3 += bhi2f(v.y);
  }
  for (int j = s + 32; j < e; ++j) {     // rare degree>32 remainder
    int sr = ssrc[j];
    uint2 v = ((const uint2*)(fb + (size_t)sr * D))[lane];
    a0 += blo2f(v.x); a1 += bhi2f(v.x);
    a2 += blo2f(v.y); a3 += bhi2f(v.y);
  }
  float inv = (n > 0) ? 1.0f / (float)n : 0.f;
  u32 p0 = (u32)f2b(a0 * inv) | ((u32)f2b(a1 * inv) << 16);
  u32 p1 = (u32)f2b(a2 * inv) | ((u32)f2b(a3 * inv) << 16);
  u32* mrow;
  if (t == 0)      mrow = (u32*)(ob + (size_t)d * 256);              // mean_uu: row 1st half
  else if (t == 2) mrow = (u32*)(ob + (size_t)d * 256 + 128);        // mean_iu: row 2nd half
  else             mrow = (u32*)(ob + 12800000 + (size_t)d * 256);   // mean_ub: item row
  ((uint2*)mrow)[lane] = make_uint2(p0, p1);
}

// ---- final GEMM v3: B pre-staged in LDS as per-lane MFMA fragments (conflict-free
//      ds_read_b128), 2 row-tiles (32 rows) per wave so each B fragment feeds 2 MFMAs.
//      Per kk-step: 2 VMEM A-loads + 8 DS reads + 16 MFMAs (was 9 VMEM + 8 MFMA).
//      In-place on d_out: used A-reads are always of the wave's own rows; OOB-clamped
//      reads produce discarded results only. ----
__global__ void __launch_bounds__(256, 2) k_out(float* out, const u16* __restrict__ WT,
                                                const float* __restrict__ buu, const float* __restrict__ bub,
                                                const float* __restrict__ biu, const int* __restrict__ off) {
  int users = (blockIdx.y == 0);
  int tid = threadIdx.x;
  int w = tid >> 6, lane = tid & 63, quad = lane >> 4, l16 = lane & 15;
  int KT = users ? 8 : 4;                        // K/32 tiles (K=256 user, 128 item)
  const u16* Wsrc = users ? WT : (WT + 32768);
  int wstride = users ? 256 : 128;               // u16 per WT row

  // stage B fragments: sB[((kk*8+nt)*64+lane)*8 u16] = 16B fragment for (kk,nt,lane)
  __shared__ u16 sB[32768];                      // 64 KB (user); item uses first 32 KB
  int nfrag = KT * 8 * 64;
  for (int fid = tid; fid < nfrag; fid += 256) {
    int fl = fid & 63, fnt = (fid >> 6) & 7, fkk = fid >> 9;
    int fq = fl >> 4, fl16 = fl & 15;
    const u16* src = Wsrc + (fnt * 16 + fl16) * wstride + fkk * 32 + fq * 8;
    *(uint4*)(sB + (size_t)fid * 8) = *(const uint4*)src;
  }
  __syncthreads();

  int row0 = blockIdx.x * 128 + w * 32;          // wave's 32 rows (2 tiles of 16)
  const u16* ob = (const u16*)out;
  const u16* Abase = users ? ob : (ob + 12800000);
  size_t outoff = users ? 0 : (size_t)N_USER;

  int r0a = row0 + l16, r1a = row0 + 16 + l16;
  int rA0 = r0a < N_USER ? r0a : N_USER - 1;
  int rA1 = r1a < N_USER ? r1a : N_USER - 1;
  const u16* A0 = Abase + (size_t)rA0 * 256 + quad * 8;
  const u16* A1 = Abase + (size_t)rA1 * 256 + quad * 8;

  floatx4 acc[2][8];
#pragma unroll
  for (int rt = 0; rt < 2; ++rt)
#pragma unroll
    for (int nt = 0; nt < 8; ++nt) acc[rt][nt] = (floatx4){0.f, 0.f, 0.f, 0.f};

  for (int kk = 0; kk < KT; ++kk) {
    short8 af0 = *(const short8*)(A0 + kk * 32);
    short8 af1 = *(const short8*)(A1 + kk * 32);
    const short8* bp = (const short8*)(sB + ((size_t)kk * 8 * 64 + lane) * 8);
#pragma unroll
    for (int nt = 0; nt < 8; ++nt) {
      short8 bf = bp[nt * 64];
      acc[0][nt] = __builtin_amdgcn_mfma_f32_16x16x32_bf16(af0, bf, acc[0][nt], 0, 0, 0);
      acc[1][nt] = __builtin_amdgcn_mfma_f32_16x16x32_bf16(af1, bf, acc[1][nt], 0, 0, 0);
    }
  }

#pragma unroll
  for (int rt = 0; rt < 2; ++rt) {
    int tbase = row0 + rt * 16;
    int nA[4], nB[4];
#pragma unroll
    for (int i = 0; i < 4; ++i) {
      int grow = tbase + quad * 4 + i;
      bool ok = grow < N_USER;
      if (users) {
        nA[i] = ok ? (off[grow + 1] - off[grow]) : 0;                             // uu
        nB[i] = ok ? (off[2 * N_USER + grow + 1] - off[2 * N_USER + grow]) : 0;   // iu
      } else {
        nA[i] = ok ? (off[N_USER + grow + 1] - off[N_USER + grow]) : 0;           // ub
        nB[i] = 0;
      }
    }
#pragma unroll
    for (int nt = 0; nt < 8; ++nt) {
      int col = nt * 16 + l16;
      float bA = users ? buu[col] : bub[col];
      float bB = users ? biu[col] : 0.f;
#pragma unroll
      for (int i = 0; i < 4; ++i) {
        int grow = tbase + quad * 4 + i;
        if (grow < N_USER) {
          float r = acc[rt][nt][i] + (nA[i] > 0 ? bA : 0.f) + (nB[i] > 0 ? bB : 0.f);
          out[(outoff + (size_t)grow) * D + col] = r;
        }
      }
    }
  }
}

extern "C" void kernel_launch(void* const* d_in, const int* in_sizes, int n_in,
                              void* d_out, int out_size, void* d_ws, size_t ws_size,
                              hipStream_t stream) {
  const float* fu  = (const float*)d_in[0];
  const float* fi  = (const float*)d_in[1];
  const float* Wuu = (const float*)d_in[2];
  const float* buu = (const float*)d_in[3];
  const float* Wub = (const float*)d_in[4];
  const float* bub = (const float*)d_in[5];
  const float* Wiu = (const float*)d_in[6];
  const float* biu = (const float*)d_in[7];
  const int* suu = (const int*)d_in[8];
  const int* duu = (const int*)d_in[9];
  const int* sub = (const int*)d_in[10];
  const int* dub = (const int*)d_in[11];
  const int* siu = (const int*)d_in[12];
  const int* diu = (const int*)d_in[13];
  float* out = (float*)d_out;   // f32: [out_user 50000x128 | out_item 50000x128]
  u16* ob = (u16*)d_out;
  // d_out scratch (race-free): k_mean writes bf16 means INTO the output rows
  //   user row r: [0,256B)=mean_uu, [256B,512B)=mean_iu ; item row r: [0,256B)=mean_ub
  // k_out waves read only their own rows' means (used values), then overwrite them.

  // workspace layout (37.1 MB), offsets in INTs (verified r3):
  //   WT = 49,152 u16 = 24,576 ints; fb_u = 6,400,000 u16 = 3,200,000 ints
  int* wsi    = (int*)d_ws;
  int* off    = wsi;                        // [150001] -> pad to 150016
  int* bhist  = wsi + 150016;               // [147]
  int* cursor = wsi + 150208;               // [147]
  int* boff   = wsi + 150400;               // [148]
  u32* ebuf   = (u32*)(wsi + 150592);       // [1800000] (7.2 MB)
  u16* ssrc   = (u16*)(wsi + 1950592);      // [1800000] u16 (3.6 MB)
  u16* WT     = (u16*)(wsi + 2850592);      // WTu 32768 + WTi 16384 u16 (96 KB)
  u16* fb_u   = (u16*)(wsi + 2875168);      // 50000x128 bf16 row-major (12.8 MB)
  u16* fb_i   = (u16*)(wsi + 6075168);      // 50000x128 bf16 row-major (12.8 MB)

  hipMemsetAsync(bhist, 0, 384 * sizeof(int), stream);   // bhist + cursor
  k_front<<<443 + 12500, 256, 0, stream>>>(duu, dub, diu, bhist, Wuu, Wub, Wiu, WT,
                                           fu, fi, fb_u, fb_i);
  k_bplace<<<440, 256, 0, stream>>>(suu, duu, sub, dub, siu, diu, bhist, cursor, boff, ebuf);
  k_csr<<<NB, 256, 0, stream>>>(boff, ebuf, off, ssrc);
  k_mean<<<18750, 256, 0, stream>>>(fb_u, fb_i, off, ssrc, ob);
  k_out<<<dim3(391, 2), 256, 0, stream>>>(out, WT, buu, bub, biu, off);
}

// Round 9
// 279.920 us; speedup vs baseline: 1.7339x; 1.0232x over previous
//
#include <hip/hip_runtime.h>
#include <stdint.h>
#include <string.h>

#define N_USER 50000
#define N_ITEM 50000
#define N_EDGE 600000
#define D 128
#define NTOT 150000      // 3 * 50000 destination slots (uu | ub | iu)
#define ETOT 1800000
#define NB 293           // buckets = ceil(NTOT / SPAN)
#define BSH 9
#define SPAN 512         // slots per bucket
#define CHUNK 4096       // edges per block in bucket kernels (16/thread)

typedef unsigned short u16;
typedef unsigned int   u32;
typedef __attribute__((ext_vector_type(8))) short short8;   // 8 bf16 (MFMA A/B frag)
typedef __attribute__((ext_vector_type(4))) float floatx4;  // MFMA C/D frag

static __device__ __forceinline__ u16 f2b(float f) {        // f32 -> bf16 RNE
  u32 x; memcpy(&x, &f, 4);
  u32 r = x + 0x7fffu + ((x >> 16) & 1u);
  return (u16)(r >> 16);
}
static __device__ __forceinline__ float blo2f(u32 v) {
  u32 x = v << 16; float f; memcpy(&f, &x, 4); return f;
}
static __device__ __forceinline__ float bhi2f(u32 v) {
  u32 x = v & 0xffff0000u; float f; memcpy(&f, &x, 4); return f;
}

// ---- front: [0,440) edge-bucket histogram | [440,443) weight transpose (stacked) |
//      [443,2006) grid-stride f32->bf16 feature conversion (8 float4/thread) ----
// WTu = [W_uu ; W_iu]^T as [n=128][k=256]; WTi = W_ub^T as [n=128][k=128] at +32768 u16.
__global__ void __launch_bounds__(256) k_front(
    const int* __restrict__ duu, const int* __restrict__ dub, const int* __restrict__ diu,
    int* __restrict__ bhist,
    const float* __restrict__ W0, const float* __restrict__ W1, const float* __restrict__ W2,
    u16* __restrict__ WT,
    const float* __restrict__ fu, const float* __restrict__ fi,
    u16* __restrict__ fb_u, u16* __restrict__ fb_i) {
  int bid = blockIdx.x;
  if (bid < 440) {                       // bucket histogram
    __shared__ int h[NB];
    for (int i = threadIdx.x; i < NB; i += 256) h[i] = 0;
    __syncthreads();
    int base = bid * CHUNK;
    for (int j = threadIdx.x; j < CHUNK; j += 256) {
      int e = base + j;
      if (e < ETOT) {
        int t = e / N_EDGE, i = e - t * N_EDGE;
        int d = (t == 0) ? duu[i] : ((t == 1) ? dub[i] : diu[i]);
        atomicAdd(&h[(t * N_USER + d) >> BSH], 1);
      }
    }
    __syncthreads();
    for (int i = threadIdx.x; i < NB; i += 256) if (h[i]) atomicAdd(&bhist[i], h[i]);
  } else if (bid < 443) {                // weight transpose + bf16 (stacked layout)
    int wsel = bid - 440;
    for (int idx = threadIdx.x; idx < D * D; idx += 256) {
      int n = idx >> 7, k = idx & 127;
      if (wsel == 0)      WT[n * 256 + k]       = f2b(W0[k * D + n]);   // W_uu -> WTu k<128
      else if (wsel == 1) WT[n * 256 + 128 + k] = f2b(W2[k * D + n]);   // W_iu -> WTu k>=128
      else                WT[32768 + n * D + k] = f2b(W1[k * D + n]);   // W_ub -> WTi
    }
  } else {                               // feature conversion, grid-stride 8x float4
    int base = (bid - 443) * 2048;
#pragma unroll
    for (int u = 0; u < 8; ++u) {
      int gid = base + u * 256 + threadIdx.x;     // 3.2M float4 groups total
      if (gid < 3200000) {
        const float* src = fu; u16* dst = fb_u; int g = gid;
        if (g >= 1600000) { g -= 1600000; src = fi; dst = fb_i; }
        float4 v = ((const float4*)src)[g];
        union { u16 u[4]; uint2 d; } pk;
        pk.u[0] = f2b(v.x); pk.u[1] = f2b(v.y); pk.u[2] = f2b(v.z); pk.u[3] = f2b(v.w);
        ((uint2*)dst)[g] = pk.d;
      }
    }
  }
}

// ---- place edges into bucket-grouped ebuf; each block re-derives the bucket scan
//      (NB=293 > 256: 2-elements-per-thread 512-wide scan); block 0 publishes boff ----
__global__ void __launch_bounds__(256) k_bplace(
    const int* __restrict__ suu, const int* __restrict__ duu,
    const int* __restrict__ sub, const int* __restrict__ dub,
    const int* __restrict__ siu, const int* __restrict__ diu,
    const int* __restrict__ bhist, int* __restrict__ cursor,
    int* __restrict__ boff, u32* __restrict__ ebuf) {
  __shared__ int h[NB];
  __shared__ int sboff[NB];
  __shared__ int buf[256];
  int t = threadIdx.x;
  int a = (2 * t < NB) ? bhist[2 * t] : 0;
  int b = (2 * t + 1 < NB) ? bhist[2 * t + 1] : 0;
  buf[t] = a + b; __syncthreads();
  for (int s = 1; s < 256; s <<= 1) {
    int y = (t >= s) ? buf[t - s] : 0;
    __syncthreads(); buf[t] += y; __syncthreads();
  }
  int ex = buf[t] - (a + b);                 // exclusive prefix of pair base
  if (2 * t < NB) sboff[2 * t] = ex;
  if (2 * t + 1 < NB) sboff[2 * t + 1] = ex + a;
  if (blockIdx.x == 0) {
    if (2 * t < NB) boff[2 * t] = ex;
    if (2 * t + 1 < NB) boff[2 * t + 1] = ex + a;
    if (t == 255) boff[NB] = buf[255];       // total = ETOT
  }
  for (int i = t; i < NB; i += 256) h[i] = 0;
  __syncthreads();
  int base = blockIdx.x * CHUNK;
  u32 pay[16], br[16];
#pragma unroll
  for (int k = 0; k < 16; ++k) {
    int e = base + k * 256 + t;
    br[k] = 0xFFFFFFFFu;
    if (e < ETOT) {
      int ty = e / N_EDGE, i = e - ty * N_EDGE;
      int d, s;
      if (ty == 0)      { d = duu[i]; s = suu[i]; }
      else if (ty == 1) { d = dub[i]; s = sub[i]; }
      else              { d = diu[i]; s = siu[i]; }
      int slot = ty * N_USER + d;
      int bu = slot >> BSH;
      int rank = atomicAdd(&h[bu], 1);
      pay[k] = (u32)s | ((u32)(slot & (SPAN - 1)) << 16);
      br[k]  = (u32)bu | ((u32)rank << 9);       // bu<=292 fits 9 bits; rank<4096
    }
  }
  __syncthreads();
  for (int i = t; i < NB; i += 256)
    h[i] = sboff[i] + atomicAdd(&cursor[i], h[i]);    // block base within bucket region
  __syncthreads();
#pragma unroll
  for (int k = 0; k < 16; ++k) {
    if (br[k] != 0xFFFFFFFFu) {
      int bu = br[k] & 0x1FF, rank = (int)(br[k] >> 9);
      ebuf[h[bu] + rank] = pay[k];
    }
  }
}

// ---- per-bucket CSR finalize (SPAN=512, 2 slots/thread): off[] + ssrc[] ----
__global__ void __launch_bounds__(256) k_csr(const int* __restrict__ boff, const u32* __restrict__ ebuf,
                                             int* __restrict__ off, u16* __restrict__ ssrc) {
  __shared__ int sc[SPAN];
  __shared__ int so[SPAN];
  __shared__ int part[256];
  int b = blockIdx.x;
  int ebase = boff[b], ecnt = boff[b + 1] - ebase;
  int sbase = b << BSH;
  int nslots = (NTOT - sbase < SPAN) ? (NTOT - sbase) : SPAN;
  for (int i = threadIdx.x; i < SPAN; i += 256) sc[i] = 0;
  __syncthreads();
  for (int j = threadIdx.x; j < ecnt; j += 256)
    atomicAdd(&sc[ebuf[ebase + j] >> 16], 1);
  __syncthreads();
  int t = threadIdx.x;
  int s0 = sc[2 * t], s1 = sc[2 * t + 1];
  int tsum = s0 + s1;
  part[t] = tsum; __syncthreads();
  for (int s = 1; s < 256; s <<= 1) {
    int y = (t >= s) ? part[t - s] : 0;
    __syncthreads(); part[t] += y; __syncthreads();
  }
  int pbase = part[t] - tsum;
  so[2 * t]     = pbase;
  so[2 * t + 1] = pbase + s0;
  __syncthreads();
  for (int i = threadIdx.x; i < nslots; i += 256)
    off[sbase + i] = ebase + so[i];
  if (b == 0 && threadIdx.x == 0) off[NTOT] = ETOT;
  for (int i = threadIdx.x; i < SPAN; i += 256) sc[i] = so[i];   // cursors
  __syncthreads();
  for (int j = threadIdx.x; j < ecnt; j += 256) {
    u32 p = ebuf[ebase + j];
    int pos = atomicAdd(&sc[p >> 16], 1);
    ssrc[ebase + pos] = (u16)(p & 0xFFFFu);
  }
}

// ---- gather-mean v3: HALF-wave (32 lanes) per slot, uint2 (8B) per lane per row.
//      Edge indices preloaded once, broadcast via __shfl on the LDS pipe. ----
__global__ void __launch_bounds__(256) k_mean(const u16* __restrict__ fb_u, const u16* __restrict__ fb_i,
                                              const int* __restrict__ off, const u16* __restrict__ ssrc,
                                              u16* __restrict__ ob) {
  int slot = blockIdx.x * 8 + (threadIdx.x >> 5);
  int lane = threadIdx.x & 31;
  if (slot >= NTOT) return;
  int t = slot / N_USER;
  int d = slot - t * N_USER;
  const u16* fb = (t == 2) ? fb_i : fb_u;
  int s = off[slot], e = off[slot + 1];
  int n = e - s;
  int my_src = (lane < n) ? (int)ssrc[s + lane] : 0;   // preload up to 32 edge srcs
  float a0 = 0.f, a1 = 0.f, a2 = 0.f, a3 = 0.f;
  int m = (n < 32) ? n : 32;
  int i = 0;
  for (; i + 4 <= m; i += 4) {
    int s0 = __shfl(my_src, i, 32);
    int s1 = __shfl(my_src, i + 1, 32);
    int s2 = __shfl(my_src, i + 2, 32);
    int s3 = __shfl(my_src, i + 3, 32);
    uint2 v0 = ((const uint2*)(fb + (size_t)s0 * D))[lane];
    uint2 v1 = ((const uint2*)(fb + (size_t)s1 * D))[lane];
    uint2 v2 = ((const uint2*)(fb + (size_t)s2 * D))[lane];
    uint2 v3 = ((const uint2*)(fb + (size_t)s3 * D))[lane];
    a0 += blo2f(v0.x) + blo2f(v1.x) + blo2f(v2.x) + blo2f(v3.x);
    a1 += bhi2f(v0.x) + bhi2f(v1.x) + bhi2f(v2.x) + bhi2f(v3.x);
    a2 += blo2f(v0.y) + blo2f(v1.y) + blo2f(v2.y) + blo2f(v3.y);
    a3 += bhi2f(v0.y) + bhi2f(v1.y) + bhi2f(v2.y) + bhi2f(v3.y);
  }
  for (; i < m; ++i) {
    int sr = __shfl(my_src, i, 32);
    uint2 v = ((const uint2*)(fb + (size_t)sr * D))[lane];
    a0 += blo2f(v.x); a1 += bhi2f(v.x);
    a2 += blo2f(v.y); a3 += bhi2f(v.y);
  }
  for (int j = s + 32; j < e; ++j) {     // rare degree>32 remainder
    int sr = ssrc[j];
    uint2 v = ((const uint2*)(fb + (size_t)sr * D))[lane];
    a0 += blo2f(v.x); a1 += bhi2f(v.x);
    a2 += blo2f(v.y); a3 += bhi2f(v.y);
  }
  float inv = (n > 0) ? 1.0f / (float)n : 0.f;
  u32 p0 = (u32)f2b(a0 * inv) | ((u32)f2b(a1 * inv) << 16);
  u32 p1 = (u32)f2b(a2 * inv) | ((u32)f2b(a3 * inv) << 16);
  u32* mrow;
  if (t == 0)      mrow = (u32*)(ob + (size_t)d * 256);              // mean_uu: row 1st half
  else if (t == 2) mrow = (u32*)(ob + (size_t)d * 256 + 128);        // mean_iu: row 2nd half
  else             mrow = (u32*)(ob + 12800000 + (size_t)d * 256);   // mean_ub: item row
  ((uint2*)mrow)[lane] = make_uint2(p0, p1);
}

// ---- final GEMM v4: LDS-staged B fragments + ALL A-fragment and gate loads hoisted
//      BEFORE the barrier (HBM latency overlaps staging; __syncthreads drains them).
//      MFMA loop is then pure LDS+MFMA. 2 row-tiles (32 rows) per wave. ----
__global__ void __launch_bounds__(256, 2) k_out(float* out, const u16* __restrict__ WT,
                                                const float* __restrict__ buu, const float* __restrict__ bub,
                                                const float* __restrict__ biu, const int* __restrict__ off) {
  int users = (blockIdx.y == 0);
  int tid = threadIdx.x;
  int w = tid >> 6, lane = tid & 63, quad = lane >> 4, l16 = lane & 15;
  int KT = users ? 8 : 4;                        // K/32 tiles (K=256 user, 128 item)
  const u16* Wsrc = users ? WT : (WT + 32768);
  int wstride = users ? 256 : 128;               // u16 per WT row

  // stage B fragments: sB[((kk*8+nt)*64+lane)*8 u16] = 16B fragment for (kk,nt,lane)
  __shared__ u16 sB[32768];                      // 64 KB (user); item uses first 32 KB
  int nfrag = KT * 8 * 64;
  for (int fid = tid; fid < nfrag; fid += 256) {
    int fl = fid & 63, fnt = (fid >> 6) & 7, fkk = fid >> 9;
    int fq = fl >> 4, fl16 = fl & 15;
    const u16* src = Wsrc + (fnt * 16 + fl16) * wstride + fkk * 32 + fq * 8;
    *(uint4*)(sB + (size_t)fid * 8) = *(const uint4*)src;
  }

  int row0 = blockIdx.x * 128 + w * 32;          // wave's 32 rows (2 tiles of 16)
  const u16* ob = (const u16*)out;
  const u16* Abase = users ? ob : (ob + 12800000);
  size_t outoff = users ? 0 : (size_t)N_USER;

  int r0a = row0 + l16, r1a = row0 + 16 + l16;
  int rA0 = r0a < N_USER ? r0a : N_USER - 1;
  int rA1 = r1a < N_USER ? r1a : N_USER - 1;
  const u16* A0 = Abase + (size_t)rA0 * 256 + quad * 8;
  const u16* A1 = Abase + (size_t)rA1 * 256 + quad * 8;

  // hoist all A-fragment loads (issued before the barrier drains VMEM)
  short8 af0[8], af1[8];
#pragma unroll
  for (int kk = 0; kk < 8; ++kk) {
    if (kk < KT) {
      af0[kk] = *(const short8*)(A0 + kk * 32);
      af1[kk] = *(const short8*)(A1 + kk * 32);
    }
  }
  // hoist degree-gate loads too
  int nA[2][4], nB[2][4];
#pragma unroll
  for (int rt = 0; rt < 2; ++rt)
#pragma unroll
    for (int i = 0; i < 4; ++i) {
      int grow = row0 + rt * 16 + quad * 4 + i;
      bool ok = grow < N_USER;
      if (users) {
        nA[rt][i] = ok ? (off[grow + 1] - off[grow]) : 0;                             // uu
        nB[rt][i] = ok ? (off[2 * N_USER + grow + 1] - off[2 * N_USER + grow]) : 0;   // iu
      } else {
        nA[rt][i] = ok ? (off[N_USER + grow + 1] - off[N_USER + grow]) : 0;           // ub
        nB[rt][i] = 0;
      }
    }
  __syncthreads();

  floatx4 acc[2][8];
#pragma unroll
  for (int rt = 0; rt < 2; ++rt)
#pragma unroll
    for (int nt = 0; nt < 8; ++nt) acc[rt][nt] = (floatx4){0.f, 0.f, 0.f, 0.f};

#pragma unroll
  for (int kk = 0; kk < 8; ++kk) {
    if (kk < KT) {
      const short8* bp = (const short8*)(sB + ((size_t)kk * 512 + lane) * 8);
#pragma unroll
      for (int nt = 0; nt < 8; ++nt) {
        short8 bf = bp[nt * 64];
        acc[0][nt] = __builtin_amdgcn_mfma_f32_16x16x32_bf16(af0[kk], bf, acc[0][nt], 0, 0, 0);
        acc[1][nt] = __builtin_amdgcn_mfma_f32_16x16x32_bf16(af1[kk], bf, acc[1][nt], 0, 0, 0);
      }
    }
  }

#pragma unroll
  for (int rt = 0; rt < 2; ++rt) {
    int tbase = row0 + rt * 16;
#pragma unroll
    for (int nt = 0; nt < 8; ++nt) {
      int col = nt * 16 + l16;
      float bA = users ? buu[col] : bub[col];
      float bB = users ? biu[col] : 0.f;
#pragma unroll
      for (int i = 0; i < 4; ++i) {
        int grow = tbase + quad * 4 + i;
        if (grow < N_USER) {
          float r = acc[rt][nt][i] + (nA[rt][i] > 0 ? bA : 0.f) + (nB[rt][i] > 0 ? bB : 0.f);
          out[(outoff + (size_t)grow) * D + col] = r;
        }
      }
    }
  }
}

extern "C" void kernel_launch(void* const* d_in, const int* in_sizes, int n_in,
                              void* d_out, int out_size, void* d_ws, size_t ws_size,
                              hipStream_t stream) {
  const float* fu  = (const float*)d_in[0];
  const float* fi  = (const float*)d_in[1];
  const float* Wuu = (const float*)d_in[2];
  const float* buu = (const float*)d_in[3];
  const float* Wub = (const float*)d_in[4];
  const float* bub = (const float*)d_in[5];
  const float* Wiu = (const float*)d_in[6];
  const float* biu = (const float*)d_in[7];
  const int* suu = (const int*)d_in[8];
  const int* duu = (const int*)d_in[9];
  const int* sub = (const int*)d_in[10];
  const int* dub = (const int*)d_in[11];
  const int* siu = (const int*)d_in[12];
  const int* diu = (const int*)d_in[13];
  float* out = (float*)d_out;   // f32: [out_user 50000x128 | out_item 50000x128]
  u16* ob = (u16*)d_out;
  // d_out scratch (race-free): k_mean writes bf16 means INTO the output rows
  //   user row r: [0,256B)=mean_uu, [256B,512B)=mean_iu ; item row r: [0,256B)=mean_ub
  // k_out waves read only their own rows' means (used values), then overwrite them.

  // workspace layout (37.1 MB), offsets in INTs:
  //   off 150016 | bhist 320 | cursor 320 | boff 320 | ebuf 1.8M | ssrc 900000 |
  //   WT 24576 | fb_u 3.2M | fb_i 3.2M  -> ends at 9,275,552 ints
  int* wsi    = (int*)d_ws;
  int* off    = wsi;                        // [150001] -> pad to 150016
  int* bhist  = wsi + 150016;               // [293] pad 320
  int* cursor = wsi + 150336;               // [293] pad 320
  int* boff   = wsi + 150656;               // [294] pad 320
  u32* ebuf   = (u32*)(wsi + 150976);       // [1800000] (7.2 MB)
  u16* ssrc   = (u16*)(wsi + 1950976);      // [1800000] u16 (3.6 MB)
  u16* WT     = (u16*)(wsi + 2850976);      // WTu 32768 + WTi 16384 u16 (96 KB)
  u16* fb_u   = (u16*)(wsi + 2875552);      // 50000x128 bf16 row-major (12.8 MB)
  u16* fb_i   = (u16*)(wsi + 6075552);      // 50000x128 bf16 row-major (12.8 MB)

  hipMemsetAsync(bhist, 0, 640 * sizeof(int), stream);   // bhist + cursor
  k_front<<<443 + 1563, 256, 0, stream>>>(duu, dub, diu, bhist, Wuu, Wub, Wiu, WT,
                                          fu, fi, fb_u, fb_i);
  k_bplace<<<440, 256, 0, stream>>>(suu, duu, sub, dub, siu, diu, bhist, cursor, boff, ebuf);
  k_csr<<<NB, 256, 0, stream>>>(boff, ebuf, off, ssrc);
  k_mean<<<18750, 256, 0, stream>>>(fb_u, fb_i, off, ssrc, ob);
  k_out<<<dim3(391, 2), 256, 0, stream>>>(out, WT, buu, bub, biu, off);
}